// Round 12
// baseline (498.936 us; speedup 1.0000x reference)
//
#include <hip/hip_runtime.h>
#include <hip/hip_bf16.h>

#define S_LEN 4096
#define DMODEL 2048
#define NHEADS 16
#define HEADDIM 128
#define LDQ 6144  // stride of fused QKV buffer

typedef __attribute__((ext_vector_type(8))) short bf16x8;
typedef __attribute__((ext_vector_type(4))) float f32x4;

__device__ __forceinline__ float bf2f(ushort u) {
  union { unsigned int i; float f; } x; x.i = ((unsigned int)u) << 16; return x.f;
}
__device__ __forceinline__ ushort f2bf(float f) {
  union { float f; unsigned int i; } x; x.f = f;
  unsigned int u = x.i;
  unsigned int r = u + 0x7fffu + ((u >> 16) & 1u);
  return (ushort)(r >> 16);
}
__device__ __forceinline__ unsigned int cvtpk(float a, float b) {
  unsigned int r;
  asm("v_cvt_pk_bf16_f32 %0, %1, %2" : "=v"(r) : "v"(a), "v"(b));
  return r;
}
// fast hardware exp2 (v_exp_f32 IS 2^x)
__device__ __forceinline__ float fexp2(float x) {
  float r;
  asm("v_exp_f32 %0, %1" : "=v"(r) : "v"(x));
  return r;
}

__device__ __forceinline__ void gload16(const ushort* g, ushort* l) {
  __builtin_amdgcn_global_load_lds(
      (const __attribute__((address_space(1))) unsigned int*)g,
      (__attribute__((address_space(3))) unsigned int*)l, 16, 0, 0);
}

// ---------------- RoPE cos/sin table ----------------
__global__ __launch_bounds__(256) void rope_table_kernel(float* __restrict__ cosT,
                                                         float* __restrict__ sinT) {
  int idx = blockIdx.x * 256 + threadIdx.x;
  int t = idx >> 6, j = idx & 63;
  float expo = (float)(2 * j) / 128.0f;
  float inv = 1.0f / powf(10000.0f, expo);
  float f = (float)t * inv;
  cosT[idx] = cosf(f);
  sinT[idx] = sinf(f);
}

// ---------------- fp32 -> bf16 (RNE) convert ----------------
__global__ __launch_bounds__(256) void convert_kernel(const float* __restrict__ in,
                                                      ushort* __restrict__ hi) {
  int i = (blockIdx.x * 256 + threadIdx.x) * 4;
  float4 v = *reinterpret_cast<const float4*>(&in[i]);
  ushort4 h;
  h.x = f2bf(v.x); h.y = f2bf(v.y); h.z = f2bf(v.z); h.w = f2bf(v.w);
  *reinterpret_cast<ushort4*>(&hi[i]) = h;
}

// ---------------- weight prep ----------------
__global__ __launch_bounds__(256) void prep_weights(const float* __restrict__ Wq,
                                                    const float* __restrict__ Wk,
                                                    const float* __restrict__ Wv,
                                                    const float* __restrict__ Wo,
                                                    ushort* __restrict__ Wqkv,
                                                    ushort* __restrict__ Woh) {
  int i = (blockIdx.x * 256 + threadIdx.x) * 4;
  int which = blockIdx.y;
  const float* src = (which == 0) ? Wq : (which == 1) ? Wk : (which == 2) ? Wv : Wo;
  ushort* dst = (which == 3) ? Woh : (Wqkv + (size_t)which * DMODEL * DMODEL);
  float4 v = *reinterpret_cast<const float4*>(&src[i]);
  ushort4 h;
  h.x = f2bf(v.x); h.y = f2bf(v.y); h.z = f2bf(v.z); h.w = f2bf(v.w);
  *reinterpret_cast<ushort4*>(&dst[i]) = h;
}

// ---------------- fused QKV GEMM (unchanged) ----------------
__global__ __launch_bounds__(256) void gemm_qkv(const ushort* __restrict__ Ah_,
                                                const ushort* __restrict__ Bh_,
                                                ushort* __restrict__ Cout,
                                                int M, int N, int K) {
  __shared__ __align__(16) ushort sAh[128 * 64], sBh[128 * 64];
  const int tid = threadIdx.x;
  const int wave = tid >> 6, lane = tid & 63;
  const int lg = lane >> 4, lm = lane & 15;
  const int nwg = gridDim.x * gridDim.y;
  const int id = blockIdx.y * gridDim.x + blockIdx.x;
  const int cpx = nwg >> 3;
  const int swz = (id & 7) * cpx + (id >> 3);
  const int nbx = N >> 7;
  const int m0 = (swz / nbx) * 128, n0 = (swz % nbx) * 128;
  const int wm = (wave >> 1) * 64, wn = (wave & 1) * 64;
  f32x4 acc[4][4] = {};

  int srow[4], scc[4], lbs[4];
#pragma unroll
  for (int it = 0; it < 4; ++it) {
    int ci = it * 256 + wave * 64 + lane;
    srow[it] = ci >> 3;
    scc[it] = (ci & 7) ^ (srow[it] & 7);
    lbs[it] = (it * 256 + wave * 64) * 8;
  }

  for (int k0 = 0; k0 < K; k0 += 64) {
    __syncthreads();
#pragma unroll
    for (int it = 0; it < 4; ++it) {
      size_t ga = (size_t)(m0 + srow[it]) * K + k0 + scc[it] * 8;
      size_t gb = (size_t)(n0 + srow[it]) * K + k0 + scc[it] * 8;
      gload16(&Ah_[ga], &sAh[lbs[it]]);
      gload16(&Bh_[gb], &sBh[lbs[it]]);
    }
    __syncthreads();
    bf16x8 ah[4][2], bh[4][2];
#pragma unroll
    for (int t = 0; t < 4; ++t)
#pragma unroll
      for (int kc = 0; kc < 2; ++kc) {
        int Ra = wm + t * 16 + lm;
        int Rb = wn + t * 16 + lm;
        int pa_ = ((kc * 4 + lg) ^ (Ra & 7)) * 8;
        int pb_ = ((kc * 4 + lg) ^ (Rb & 7)) * 8;
        ah[t][kc] = *reinterpret_cast<const bf16x8*>(&sAh[Ra * 64 + pa_]);
        bh[t][kc] = *reinterpret_cast<const bf16x8*>(&sBh[Rb * 64 + pb_]);
      }
#pragma unroll
    for (int kc = 0; kc < 2; ++kc)
#pragma unroll
      for (int mi = 0; mi < 4; ++mi)
#pragma unroll
        for (int ni = 0; ni < 4; ++ni)
          acc[mi][ni] = __builtin_amdgcn_mfma_f32_16x16x32_bf16(ah[mi][kc], bh[ni][kc], acc[mi][ni], 0, 0, 0);
  }
#pragma unroll
  for (int mi = 0; mi < 4; ++mi)
#pragma unroll
    for (int ni = 0; ni < 4; ++ni)
#pragma unroll
      for (int j = 0; j < 4; ++j) {
        int row = m0 + wm + mi * 16 + lg * 4 + j;
        int col = n0 + wn + ni * 16 + lm;
        Cout[(size_t)row * N + col] = f2bf(acc[mi][ni][j]);
      }
}

// ---------------- 1-term final GEMM (unchanged) ----------------
__global__ __launch_bounds__(256) void gemm1o(const ushort* __restrict__ Ah_,
                                              const ushort* __restrict__ Bh_,
                                              float* __restrict__ Cout,
                                              int M, int N, int K) {
  __shared__ __align__(16) ushort sAh[128 * 32], sBh[128 * 32];
  const int tid = threadIdx.x;
  const int wave = tid >> 6, lane = tid & 63;
  const int lg = lane >> 4, lm = lane & 15;
  const int nwg = gridDim.x * gridDim.y;
  const int id = blockIdx.y * gridDim.x + blockIdx.x;
  const int cpx = nwg >> 3;
  const int swz = (id & 7) * cpx + (id >> 3);
  const int nbx = N >> 7;
  const int m0 = (swz / nbx) * 128, n0 = (swz % nbx) * 128;
  const int wm = (wave >> 1) * 64, wn = (wave & 1) * 64;
  f32x4 acc[4][4] = {};

  for (int k0 = 0; k0 < K; k0 += 32) {
    __syncthreads();
#pragma unroll
    for (int t = 0; t < 2; ++t) {
      int r = wave * 32 + t * 16 + (lane >> 2);
      int ca = (lane & 3) ^ ((r >> 1) & 3);
      size_t ga = (size_t)(m0 + r) * K + k0 + ca * 8;
      size_t gb = (size_t)(n0 + r) * K + k0 + ca * 8;
      int lb = (wave * 32 + t * 16) * 32;
      gload16(&Ah_[ga], &sAh[lb]);
      gload16(&Bh_[gb], &sBh[lb]);
    }
    __syncthreads();
    bf16x8 ah[4], bh[4];
#pragma unroll
    for (int t = 0; t < 4; ++t) {
      int Ra = wm + t * 16 + lm;
      int Rb = wn + t * 16 + lm;
      int ca = (lg ^ ((Ra >> 1) & 3)) * 8;
      int cb = (lg ^ ((Rb >> 1) & 3)) * 8;
      ah[t] = *reinterpret_cast<const bf16x8*>(&sAh[Ra * 32 + ca]);
      bh[t] = *reinterpret_cast<const bf16x8*>(&sBh[Rb * 32 + cb]);
    }
#pragma unroll
    for (int mi = 0; mi < 4; ++mi)
#pragma unroll
      for (int ni = 0; ni < 4; ++ni)
        acc[mi][ni] = __builtin_amdgcn_mfma_f32_16x16x32_bf16(ah[mi], bh[ni], acc[mi][ni], 0, 0, 0);
  }
#pragma unroll
  for (int mi = 0; mi < 4; ++mi)
#pragma unroll
    for (int ni = 0; ni < 4; ++ni)
#pragma unroll
      for (int j = 0; j < 4; ++j) {
        int row = m0 + wm + mi * 16 + lg * 4 + j;
        int col = n0 + wn + ni * 16 + lm;
        Cout[(size_t)row * N + col] = acc[mi][ni][j];
      }
}

// ---------------- RoPE (vectorized, unchanged) ----------------
__global__ __launch_bounds__(256) void rope2_kernel(ushort* __restrict__ QKV,
                                                    const int* __restrict__ pos,
                                                    const float* __restrict__ cosT,
                                                    const float* __restrict__ sinT) {
  int t = blockIdx.x * 256 + threadIdx.x;
  int j0 = (t & 7) * 8;
  int hh = (t >> 3) & 15;
  int s = t >> 7;
  int p = pos[s];
  float cs[8], sn[8];
  *reinterpret_cast<float4*>(&cs[0]) = *reinterpret_cast<const float4*>(&cosT[p * 64 + j0]);
  *reinterpret_cast<float4*>(&cs[4]) = *reinterpret_cast<const float4*>(&cosT[p * 64 + j0 + 4]);
  *reinterpret_cast<float4*>(&sn[0]) = *reinterpret_cast<const float4*>(&sinT[p * 64 + j0]);
  *reinterpret_cast<float4*>(&sn[4]) = *reinterpret_cast<const float4*>(&sinT[p * 64 + j0 + 4]);
  size_t base = (size_t)s * LDQ + hh * HEADDIM + j0;
  union u8 { uint4 v; ushort e[8]; };
  u8 qa, qb, ka, kb;
  qa.v = *reinterpret_cast<const uint4*>(&QKV[base]);
  qb.v = *reinterpret_cast<const uint4*>(&QKV[base + 64]);
  ka.v = *reinterpret_cast<const uint4*>(&QKV[base + DMODEL]);
  kb.v = *reinterpret_cast<const uint4*>(&QKV[base + DMODEL + 64]);
  const float scl = 0.12751742f;  // log2(e)/sqrt(128)
#pragma unroll
  for (int e = 0; e < 8; ++e) {
    float q1 = bf2f(qa.e[e]), q2 = bf2f(qb.e[e]);
    float k1 = bf2f(ka.e[e]), k2 = bf2f(kb.e[e]);
    qa.e[e] = f2bf((q1 * cs[e] - q2 * sn[e]) * scl);
    qb.e[e] = f2bf((q2 * cs[e] + q1 * sn[e]) * scl);
    ka.e[e] = f2bf(k1 * cs[e] - k2 * sn[e]);
    kb.e[e] = f2bf(k2 * cs[e] + k1 * sn[e]);
  }
  *reinterpret_cast<uint4*>(&QKV[base]) = qa.v;
  *reinterpret_cast<uint4*>(&QKV[base + 64]) = qb.v;
  *reinterpret_cast<uint4*>(&QKV[base + DMODEL]) = ka.v;
  *reinterpret_cast<uint4*>(&QKV[base + DMODEL + 64]) = kb.v;
}

// ---------------- V transpose (unchanged) ----------------
__global__ __launch_bounds__(256) void transpose_kernel(const ushort* __restrict__ Vr,
                                                        ushort* __restrict__ Vt) {
  __shared__ __align__(16) ushort tile[64 * 72];
  int tid = threadIdx.x;
  int s0 = blockIdx.x * 64, c0 = blockIdx.y * 64;
#pragma unroll
  for (int it = 0; it < 2; ++it) {
    int i = tid + it * 256;
    int r = i >> 3, c = i & 7;
    *reinterpret_cast<uint4*>(&tile[r * 72 + c * 8]) =
        *reinterpret_cast<const uint4*>(&Vr[(size_t)(s0 + r) * LDQ + c0 + c * 8]);
  }
  __syncthreads();
#pragma unroll
  for (int it = 0; it < 2; ++it) {
    int i = tid + it * 256;
    int cr = i >> 3, sc = i & 7;
    ushort tmp[8];
#pragma unroll
    for (int j = 0; j < 8; ++j) tmp[j] = tile[(sc * 8 + j) * 72 + cr];
    *reinterpret_cast<uint4*>(&Vt[(size_t)(c0 + cr) * S_LEN + s0 + sc * 8]) =
        *reinterpret_cast<uint4*>(tmp);
  }
}

// ---------------- Flash v13: split-K (z=2) + KBLK=32, 4 blocks/CU ----------------
// Each block handles 2048 keys. Outputs UNNORMALIZED O' (bf16) + per-row m (exp2 dom) and l.
// K permutation rho32(s) = 8*lg + 4*nf + j for slot s = nf*16+lg*4+j.
// K LDS [32][128] XOR chunk swz ^(row&7); V LDS paired rows: LDS row r holds d=2r,2r+1
// as logical chunks c (d = 2r+(c>>2), keychunk=c&3), physical p = c ^ (r&7).
__global__ __launch_bounds__(256, 4) void flash13_kernel(const ushort* __restrict__ QKV,
                                                         const ushort* __restrict__ Vt,
                                                         ushort* __restrict__ Op,
                                                         float* __restrict__ Mv,
                                                         float* __restrict__ Lv) {
  __shared__ __align__(16) ushort Kt[2][32 * 128];
  __shared__ __align__(16) ushort Vs[2][64 * 64];
  const int tid = threadIdx.x;             // 0..255
  const int wave = tid >> 6, lane = tid & 63;
  const int lg = lane >> 4, lm = lane & 15;
  const int id = blockIdx.y * gridDim.x + blockIdx.x;  // 0..511
  const int z = blockIdx.z;                             // key half
  const int o = (id & 7) * 64 + (id >> 3);              // XCD swizzle
  const int h = o >> 5;
  const int q0 = (o & 31) * 128;
  const size_t kbase = (size_t)z * 2048;

  bf16x8 qh[2][4];
#pragma unroll
  for (int t2 = 0; t2 < 2; ++t2) {
    int qrow = q0 + wave * 32 + t2 * 16 + lm;
#pragma unroll
    for (int kc = 0; kc < 4; ++kc)
      qh[t2][kc] = *reinterpret_cast<const bf16x8*>(
          &QKV[(size_t)qrow * LDQ + h * HEADDIM + kc * 32 + lg * 8]);
  }

  bf16x8 ones;
#pragma unroll
  for (int i = 0; i < 8; ++i) ones[i] = (short)0x3f80;

  const ushort* Kb = QKV + DMODEL;
  const ushort* pK[2];
  const ushort* pV[2];
  int lbs[2];
#pragma unroll
  for (int k = 0; k < 2; ++k) {
    int ci = k * 256 + wave * 64 + lane;      // 512 chunks each for K and V
    // K: LDS row = ci>>4 (key slot), physical chunk = ci&15, logical = p^(row&7)
    int ks = ci >> 4;
    int kcc = (ci & 15) ^ (ks & 7);
    int krho = 8 * ((ks >> 2) & 3) + 4 * ((ks >> 4) & 1) + (ks & 3);  // rho32
    pK[k] = Kb + (kbase + krho) * LDQ + h * HEADDIM + kcc * 8;
    // V: LDS row r = ci>>3, physical p = ci&7, logical c = p^(r&7); d=2r+(c>>2), kc=c&3
    int vr = ci >> 3;
    int vc = (ci & 7) ^ (vr & 7);
    int vd = 2 * vr + (vc >> 2);
    pV[k] = Vt + (size_t)(h * HEADDIM + vd) * S_LEN + kbase + (vc & 3) * 8;
    lbs[k] = (k * 256 + wave * 64) * 8;
  }

  f32x4 oacc[2][8] = {};
  f32x4 osum[2] = {};
  float mrun[2];
#pragma unroll
  for (int t2 = 0; t2 < 2; ++t2) mrun[t2] = -3.0e38f;

#pragma unroll
  for (int k = 0; k < 2; ++k) {
    gload16(pK[k], &Kt[0][lbs[k]]);
    gload16(pV[k], &Vs[0][lbs[k]]);
  }
  __syncthreads();

  for (int t = 0; t < 64; ++t) {  // 2048 keys / 32
    const int cur = t & 1;
    if (t < 63) {
#pragma unroll
      for (int k = 0; k < 2; ++k) {
        gload16(pK[k] + (size_t)(t + 1) * 32 * LDQ, &Kt[cur ^ 1][lbs[k]]);
        gload16(pV[k] + (size_t)(t + 1) * 32, &Vs[cur ^ 1][lbs[k]]);
      }
    }
    const ushort* Kc = &Kt[cur][0];
    const ushort* Vc = &Vs[cur][0];

    // QK^T swapped: st[g][nf][j] = S[key slot nf*16+lg*4+j][q=lm]
    f32x4 st[2][2] = {};
    __builtin_amdgcn_s_setprio(1);
#pragma unroll
    for (int nf = 0; nf < 2; ++nf)
#pragma unroll
      for (int kc = 0; kc < 4; ++kc) {
        int pc = (kc * 4 + lg) ^ (lm & 7);
        bf16x8 kfrag = *reinterpret_cast<const bf16x8*>(&Kc[(nf * 16 + lm) * 128 + pc * 8]);
        st[0][nf] = __builtin_amdgcn_mfma_f32_16x16x32_bf16(kfrag, qh[0][kc], st[0][nf], 0, 0, 0);
        st[1][nf] = __builtin_amdgcn_mfma_f32_16x16x32_bf16(kfrag, qh[1][kc], st[1][nf], 0, 0, 0);
      }
    __builtin_amdgcn_s_setprio(0);

    // row max over 8 in-lane values + cross-replica
    float m16[2];
#pragma unroll
    for (int t2 = 0; t2 < 2; ++t2) {
      float m = fmaxf(st[t2][0][0], st[t2][0][1]);
      m = fmaxf(fmaxf(m, st[t2][0][2]), st[t2][0][3]);
      m = fmaxf(fmaxf(m, st[t2][1][0]), st[t2][1][1]);
      m = fmaxf(fmaxf(m, st[t2][1][2]), st[t2][1][3]);
      m = fmaxf(m, __shfl_xor(m, 16));
      m = fmaxf(m, __shfl_xor(m, 32));
      m16[t2] = m;
    }

    // defer-max rescale (exp2 domain)
    bool grow = (m16[0] > mrun[0] + 11.5f) || (m16[1] > mrun[1] + 11.5f);
    if (__any(grow)) {
#pragma unroll
      for (int t2 = 0; t2 < 2; ++t2) {
        float mn = fmaxf(mrun[t2], m16[t2]);
        float scl = fexp2(mrun[t2] - mn);
        mrun[t2] = mn;
        float sj[4];
#pragma unroll
        for (int j = 0; j < 4; ++j) sj[j] = __shfl(scl, lg * 4 + j);
#pragma unroll
        for (int j = 0; j < 4; ++j) osum[t2][j] *= sj[j];
#pragma unroll
        for (int nb = 0; nb < 8; ++nb)
#pragma unroll
          for (int j = 0; j < 4; ++j) oacc[t2][nb][j] *= sj[j];
      }
    }

    // P = exp2(S - m)
#pragma unroll
    for (int t2 = 0; t2 < 2; ++t2)
#pragma unroll
      for (int nf = 0; nf < 2; ++nf)
#pragma unroll
        for (int j = 0; j < 4; ++j)
          st[t2][nf][j] = fexp2(st[t2][nf][j] - mrun[t2]);

    // pack PV A-frag: pa[e]=p[e>>2][e&3] -> key lg*8+e
    bf16x8 pa[2];
#pragma unroll
    for (int t2 = 0; t2 < 2; ++t2) {
      union { unsigned int u[4]; bf16x8 v; } w_;
      w_.u[0] = cvtpk(st[t2][0][0], st[t2][0][1]);
      w_.u[1] = cvtpk(st[t2][0][2], st[t2][0][3]);
      w_.u[2] = cvtpk(st[t2][1][0], st[t2][1][1]);
      w_.u[3] = cvtpk(st[t2][1][2], st[t2][1][3]);
      pa[t2] = w_.v;
    }

    // PV + row-sum
    __builtin_amdgcn_s_setprio(1);
    osum[0] = __builtin_amdgcn_mfma_f32_16x16x32_bf16(pa[0], ones, osum[0], 0, 0, 0);
    osum[1] = __builtin_amdgcn_mfma_f32_16x16x32_bf16(pa[1], ones, osum[1], 0, 0, 0);
#pragma unroll
    for (int nb = 0; nb < 8; ++nb) {
      int vr = nb * 8 + (lm >> 1);
      int pc = ((lm & 1) * 4 + lg) ^ (vr & 7);
      bf16x8 vfrag = *reinterpret_cast<const bf16x8*>(&Vc[vr * 64 + pc * 8]);
      oacc[0][nb] = __builtin_amdgcn_mfma_f32_16x16x32_bf16(pa[0], vfrag, oacc[0][nb], 0, 0, 0);
      oacc[1][nb] = __builtin_amdgcn_mfma_f32_16x16x32_bf16(pa[1], vfrag, oacc[1][nb], 0, 0, 0);
    }
    __builtin_amdgcn_s_setprio(0);

    __syncthreads();
  }

  // epilogue: unnormalized O' + m + l
  Op += (size_t)z * S_LEN * DMODEL;
#pragma unroll
  for (int t2 = 0; t2 < 2; ++t2) {
#pragma unroll
    for (int nb = 0; nb < 8; ++nb)
#pragma unroll
      for (int j = 0; j < 4; ++j) {
        int row = q0 + wave * 32 + t2 * 16 + lg * 4 + j;
        int col = h * HEADDIM + nb * 16 + lm;
        Op[(size_t)row * DMODEL + col] = f2bf(oacc[t2][nb][j]);
      }
    if (lm == 0) {
#pragma unroll
      for (int j = 0; j < 4; ++j) {
        int row = q0 + wave * 32 + t2 * 16 + lg * 4 + j;
        Lv[(size_t)z * 65536 + row * 16 + h] = osum[t2][j];
      }
    }
    if (lg == 0) {
      int row = q0 + wave * 32 + t2 * 16 + lm;
      Mv[(size_t)z * 65536 + row * 16 + h] = mrun[t2];
    }
  }
}

// ---------------- combine partials: O = (w0*O0' + w1*O1') / (w0*l0 + w1*l1) ----------------
__global__ __launch_bounds__(256) void combine_kernel(const ushort* __restrict__ Op0,
                                                      const ushort* __restrict__ Op1,
                                                      const float* __restrict__ Mv,
                                                      const float* __restrict__ Lv,
                                                      ushort* __restrict__ Oh) {
  int idx = blockIdx.x * 256 + threadIdx.x;  // per 8 elems
  int q = idx >> 8;
  int col = (idx & 255) * 8;
  int h = col >> 7;
  int mi = q * 16 + h;
  float m0 = Mv[mi], m1 = Mv[65536 + mi];
  float l0 = Lv[mi], l1 = Lv[65536 + mi];
  float m = fmaxf(m0, m1);
  float w0 = fexp2(m0 - m), w1 = fexp2(m1 - m);
  float inv = 1.0f / (l0 * w0 + l1 * w1);
  w0 *= inv; w1 *= inv;
  union u8 { uint4 v; ushort e[8]; };
  u8 a, b, o;
  size_t off = (size_t)q * DMODEL + col;
  a.v = *reinterpret_cast<const uint4*>(&Op0[off]);
  b.v = *reinterpret_cast<const uint4*>(&Op1[off]);
#pragma unroll
  for (int e = 0; e < 8; ++e)
    o.e[e] = f2bf(bf2f(a.e[e]) * w0 + bf2f(b.e[e]) * w1);
  *reinterpret_cast<uint4*>(&Oh[off]) = o.v;
}

extern "C" void kernel_launch(void* const* d_in, const int* in_sizes, int n_in,
                              void* d_out, int out_size, void* d_ws, size_t ws_size,
                              hipStream_t stream) {
  (void)in_sizes; (void)n_in; (void)out_size; (void)ws_size;
  const float* X  = (const float*)d_in[0];
  const float* Wq = (const float*)d_in[1];
  const float* Wk = (const float*)d_in[2];
  const float* Wv = (const float*)d_in[3];
  const float* Wo = (const float*)d_in[4];
  const int* pos  = (const int*)d_in[5];
  float* out = (float*)d_out;

  ushort* wb = (ushort*)d_ws;
  const size_t SD = (size_t)S_LEN * DMODEL;       // 8388608 elements
  const size_t DD = (size_t)DMODEL * DMODEL;      // 4194304 elements

  ushort* Xh   = wb;                 // slot0; dead after gemm_qkv -> Op0
  ushort* Op0  = wb;                 // slot0 reuse
  ushort* Op1  = wb + SD;            // slot1
  ushort* QKV  = wb + 2 * SD;        // slots 2-4: [4096][6144]
  ushort* Vt   = wb + 5 * SD;        // slot5: [2048][4096]
  ushort* W0h  = wb + 6 * SD;        // Wo bf16
  ushort* Wqkv = wb + 7 * SD;        // [6144][2048]; dead after gemm_qkv -> OhB
  float* cosT  = (float*)(wb + 9 * SD);
  float* sinT  = cosT + (size_t)S_LEN * 64;
  // cos/sin dead after rope2 -> reuse for M/L partials (2*65536 floats each)
  float* Mv    = cosT;
  float* Lv    = cosT + 2 * 65536;
  ushort* OhB  = Wqkv;

  rope_table_kernel<<<S_LEN * 64 / 256, 256, 0, stream>>>(cosT, sinT);
  convert_kernel<<<SD / 1024, 256, 0, stream>>>(X, Xh);
  prep_weights<<<dim3(DD / 1024, 4), 256, 0, stream>>>(Wq, Wk, Wv, Wo, Wqkv, W0h);

  gemm_qkv<<<dim3(LDQ / 128, S_LEN / 128), 256, 0, stream>>>(Xh, Wqkv, QKV, S_LEN, LDQ, DMODEL);

  rope2_kernel<<<(S_LEN * 1024 / 8) / 256, 256, 0, stream>>>(QKV, pos, cosT, sinT);
  transpose_kernel<<<dim3(S_LEN / 64, DMODEL / 64), 256, 0, stream>>>(QKV + 2 * DMODEL, Vt);

  flash13_kernel<<<dim3(32, 16, 2), 256, 0, stream>>>(QKV, Vt, Op0, Mv, Lv);
  combine_kernel<<<(S_LEN * DMODEL / 8) / 256, 256, 0, stream>>>(Op0, Op1, Mv, Lv, OhB);

  dim3 gemmGrid(DMODEL / 128, S_LEN / 128);
  gemm1o<<<gemmGrid, 256, 0, stream>>>(OhB, W0h, out, S_LEN, DMODEL, DMODEL);
}

// Round 13
// 340.480 us; speedup vs baseline: 1.4654x; 1.4654x over previous
//
#include <hip/hip_runtime.h>
#include <hip/hip_bf16.h>

#define S_LEN 4096
#define DMODEL 2048
#define NHEADS 16
#define HEADDIM 128
#define LDQ 6144  // stride of fused QKV buffer

typedef __attribute__((ext_vector_type(8))) short bf16x8;
typedef __attribute__((ext_vector_type(4))) float f32x4;

__device__ __forceinline__ float bf2f(ushort u) {
  union { unsigned int i; float f; } x; x.i = ((unsigned int)u) << 16; return x.f;
}
__device__ __forceinline__ ushort f2bf(float f) {
  union { float f; unsigned int i; } x; x.f = f;
  unsigned int u = x.i;
  unsigned int r = u + 0x7fffu + ((u >> 16) & 1u);
  return (ushort)(r >> 16);
}
__device__ __forceinline__ unsigned int cvtpk(float a, float b) {
  unsigned int r;
  asm("v_cvt_pk_bf16_f32 %0, %1, %2" : "=v"(r) : "v"(a), "v"(b));
  return r;
}
// fast hardware exp2 (v_exp_f32 IS 2^x); bypasses ocml's precise path
__device__ __forceinline__ float fexp2(float x) {
  float r;
  asm("v_exp_f32 %0, %1" : "=v"(r) : "v"(x));
  return r;
}

__device__ __forceinline__ void gload16(const ushort* g, ushort* l) {
  __builtin_amdgcn_global_load_lds(
      (const __attribute__((address_space(1))) unsigned int*)g,
      (__attribute__((address_space(3))) unsigned int*)l, 16, 0, 0);
}

// ---------------- RoPE cos/sin table ----------------
__global__ __launch_bounds__(256) void rope_table_kernel(float* __restrict__ cosT,
                                                         float* __restrict__ sinT) {
  int idx = blockIdx.x * 256 + threadIdx.x;
  int t = idx >> 6, j = idx & 63;
  float expo = (float)(2 * j) / 128.0f;
  float inv = 1.0f / powf(10000.0f, expo);
  float f = (float)t * inv;
  cosT[idx] = cosf(f);
  sinT[idx] = sinf(f);
}

// ---------------- fp32 -> bf16 (RNE) convert ----------------
__global__ __launch_bounds__(256) void convert_kernel(const float* __restrict__ in,
                                                      ushort* __restrict__ hi) {
  int i = (blockIdx.x * 256 + threadIdx.x) * 4;
  float4 v = *reinterpret_cast<const float4*>(&in[i]);
  ushort4 h;
  h.x = f2bf(v.x); h.y = f2bf(v.y); h.z = f2bf(v.z); h.w = f2bf(v.w);
  *reinterpret_cast<ushort4*>(&hi[i]) = h;
}

// ---------------- weight prep: Wq/Wk/Wv -> packed bf16 [6144][2048]; Wo -> bf16 ----------------
__global__ __launch_bounds__(256) void prep_weights(const float* __restrict__ Wq,
                                                    const float* __restrict__ Wk,
                                                    const float* __restrict__ Wv,
                                                    const float* __restrict__ Wo,
                                                    ushort* __restrict__ Wqkv,
                                                    ushort* __restrict__ Woh) {
  int i = (blockIdx.x * 256 + threadIdx.x) * 4;
  int which = blockIdx.y;
  const float* src = (which == 0) ? Wq : (which == 1) ? Wk : (which == 2) ? Wv : Wo;
  ushort* dst = (which == 3) ? Woh : (Wqkv + (size_t)which * DMODEL * DMODEL);
  float4 v = *reinterpret_cast<const float4*>(&src[i]);
  ushort4 h;
  h.x = f2bf(v.x); h.y = f2bf(v.y); h.z = f2bf(v.z); h.w = f2bf(v.w);
  *reinterpret_cast<ushort4*>(&dst[i]) = h;
}

// ---------------- fused QKV GEMM: QKV = Xh * Wqkv^T, BK=64, 128x128 tile ----------------
__global__ __launch_bounds__(256) void gemm_qkv(const ushort* __restrict__ Ah_,
                                                const ushort* __restrict__ Bh_,
                                                ushort* __restrict__ Cout,
                                                int M, int N, int K) {
  __shared__ __align__(16) ushort sAh[128 * 64], sBh[128 * 64];
  const int tid = threadIdx.x;
  const int wave = tid >> 6, lane = tid & 63;
  const int lg = lane >> 4, lm = lane & 15;
  const int nwg = gridDim.x * gridDim.y;
  const int id = blockIdx.y * gridDim.x + blockIdx.x;
  const int cpx = nwg >> 3;
  const int swz = (id & 7) * cpx + (id >> 3);
  const int nbx = N >> 7;
  const int m0 = (swz / nbx) * 128, n0 = (swz % nbx) * 128;
  const int wm = (wave >> 1) * 64, wn = (wave & 1) * 64;
  f32x4 acc[4][4] = {};

  int srow[4], scc[4], lbs[4];
#pragma unroll
  for (int it = 0; it < 4; ++it) {
    int ci = it * 256 + wave * 64 + lane;
    srow[it] = ci >> 3;
    scc[it] = (ci & 7) ^ (srow[it] & 7);
    lbs[it] = (it * 256 + wave * 64) * 8;
  }

  for (int k0 = 0; k0 < K; k0 += 64) {
    __syncthreads();
#pragma unroll
    for (int it = 0; it < 4; ++it) {
      size_t ga = (size_t)(m0 + srow[it]) * K + k0 + scc[it] * 8;
      size_t gb = (size_t)(n0 + srow[it]) * K + k0 + scc[it] * 8;
      gload16(&Ah_[ga], &sAh[lbs[it]]);
      gload16(&Bh_[gb], &sBh[lbs[it]]);
    }
    __syncthreads();
    bf16x8 ah[4][2], bh[4][2];
#pragma unroll
    for (int t = 0; t < 4; ++t)
#pragma unroll
      for (int kc = 0; kc < 2; ++kc) {
        int Ra = wm + t * 16 + lm;
        int Rb = wn + t * 16 + lm;
        int pa_ = ((kc * 4 + lg) ^ (Ra & 7)) * 8;
        int pb_ = ((kc * 4 + lg) ^ (Rb & 7)) * 8;
        ah[t][kc] = *reinterpret_cast<const bf16x8*>(&sAh[Ra * 64 + pa_]);
        bh[t][kc] = *reinterpret_cast<const bf16x8*>(&sBh[Rb * 64 + pb_]);
      }
#pragma unroll
    for (int kc = 0; kc < 2; ++kc)
#pragma unroll
      for (int mi = 0; mi < 4; ++mi)
#pragma unroll
        for (int ni = 0; ni < 4; ++ni)
          acc[mi][ni] = __builtin_amdgcn_mfma_f32_16x16x32_bf16(ah[mi][kc], bh[ni][kc], acc[mi][ni], 0, 0, 0);
  }
#pragma unroll
  for (int mi = 0; mi < 4; ++mi)
#pragma unroll
    for (int ni = 0; ni < 4; ++ni)
#pragma unroll
      for (int j = 0; j < 4; ++j) {
        int row = m0 + wm + mi * 16 + lg * 4 + j;
        int col = n0 + wn + ni * 16 + lm;
        Cout[(size_t)row * N + col] = f2bf(acc[mi][ni][j]);
      }
}

// ---------------- 1-term final GEMM, BK=64 structure: out = Oh * Woh^T (f32 out) ----------------
__global__ __launch_bounds__(256) void gemm1o64(const ushort* __restrict__ Ah_,
                                                const ushort* __restrict__ Bh_,
                                                float* __restrict__ Cout,
                                                int M, int N, int K) {
  __shared__ __align__(16) ushort sAh[128 * 64], sBh[128 * 64];
  const int tid = threadIdx.x;
  const int wave = tid >> 6, lane = tid & 63;
  const int lg = lane >> 4, lm = lane & 15;
  const int nwg = gridDim.x * gridDim.y;
  const int id = blockIdx.y * gridDim.x + blockIdx.x;
  const int cpx = nwg >> 3;
  const int swz = (id & 7) * cpx + (id >> 3);
  const int nbx = N >> 7;
  const int m0 = (swz / nbx) * 128, n0 = (swz % nbx) * 128;
  const int wm = (wave >> 1) * 64, wn = (wave & 1) * 64;
  f32x4 acc[4][4] = {};

  int srow[4], scc[4], lbs[4];
#pragma unroll
  for (int it = 0; it < 4; ++it) {
    int ci = it * 256 + wave * 64 + lane;
    srow[it] = ci >> 3;
    scc[it] = (ci & 7) ^ (srow[it] & 7);
    lbs[it] = (it * 256 + wave * 64) * 8;
  }

  for (int k0 = 0; k0 < K; k0 += 64) {
    __syncthreads();
#pragma unroll
    for (int it = 0; it < 4; ++it) {
      size_t ga = (size_t)(m0 + srow[it]) * K + k0 + scc[it] * 8;
      size_t gb = (size_t)(n0 + srow[it]) * K + k0 + scc[it] * 8;
      gload16(&Ah_[ga], &sAh[lbs[it]]);
      gload16(&Bh_[gb], &sBh[lbs[it]]);
    }
    __syncthreads();
    bf16x8 ah[4][2], bh[4][2];
#pragma unroll
    for (int t = 0; t < 4; ++t)
#pragma unroll
      for (int kc = 0; kc < 2; ++kc) {
        int Ra = wm + t * 16 + lm;
        int Rb = wn + t * 16 + lm;
        int pa_ = ((kc * 4 + lg) ^ (Ra & 7)) * 8;
        int pb_ = ((kc * 4 + lg) ^ (Rb & 7)) * 8;
        ah[t][kc] = *reinterpret_cast<const bf16x8*>(&sAh[Ra * 64 + pa_]);
        bh[t][kc] = *reinterpret_cast<const bf16x8*>(&sBh[Rb * 64 + pb_]);
      }
#pragma unroll
    for (int kc = 0; kc < 2; ++kc)
#pragma unroll
      for (int mi = 0; mi < 4; ++mi)
#pragma unroll
        for (int ni = 0; ni < 4; ++ni)
          acc[mi][ni] = __builtin_amdgcn_mfma_f32_16x16x32_bf16(ah[mi][kc], bh[ni][kc], acc[mi][ni], 0, 0, 0);
  }
#pragma unroll
  for (int mi = 0; mi < 4; ++mi)
#pragma unroll
    for (int ni = 0; ni < 4; ++ni)
#pragma unroll
      for (int j = 0; j < 4; ++j) {
        int row = m0 + wm + mi * 16 + lg * 4 + j;
        int col = n0 + wn + ni * 16 + lm;
        Cout[(size_t)row * N + col] = acc[mi][ni][j];
      }
}

// ---------------- RoPE in-place on QKV buffer (vectorized x8): Q scaled by log2e/sqrt(HD) ----------------
__global__ __launch_bounds__(256) void rope2_kernel(ushort* __restrict__ QKV,
                                                    const int* __restrict__ pos,
                                                    const float* __restrict__ cosT,
                                                    const float* __restrict__ sinT) {
  int t = blockIdx.x * 256 + threadIdx.x;  // S*1024/8 threads
  int j0 = (t & 7) * 8;
  int hh = (t >> 3) & 15;
  int s = t >> 7;
  int p = pos[s];
  float cs[8], sn[8];
  *reinterpret_cast<float4*>(&cs[0]) = *reinterpret_cast<const float4*>(&cosT[p * 64 + j0]);
  *reinterpret_cast<float4*>(&cs[4]) = *reinterpret_cast<const float4*>(&cosT[p * 64 + j0 + 4]);
  *reinterpret_cast<float4*>(&sn[0]) = *reinterpret_cast<const float4*>(&sinT[p * 64 + j0]);
  *reinterpret_cast<float4*>(&sn[4]) = *reinterpret_cast<const float4*>(&sinT[p * 64 + j0 + 4]);
  size_t base = (size_t)s * LDQ + hh * HEADDIM + j0;
  union u8 { uint4 v; ushort e[8]; };
  u8 qa, qb, ka, kb;
  qa.v = *reinterpret_cast<const uint4*>(&QKV[base]);
  qb.v = *reinterpret_cast<const uint4*>(&QKV[base + 64]);
  ka.v = *reinterpret_cast<const uint4*>(&QKV[base + DMODEL]);
  kb.v = *reinterpret_cast<const uint4*>(&QKV[base + DMODEL + 64]);
  const float scl = 0.12751742f;  // log2(e)/sqrt(128)
#pragma unroll
  for (int e = 0; e < 8; ++e) {
    float q1 = bf2f(qa.e[e]), q2 = bf2f(qb.e[e]);
    float k1 = bf2f(ka.e[e]), k2 = bf2f(kb.e[e]);
    qa.e[e] = f2bf((q1 * cs[e] - q2 * sn[e]) * scl);
    qb.e[e] = f2bf((q2 * cs[e] + q1 * sn[e]) * scl);
    ka.e[e] = f2bf(k1 * cs[e] - k2 * sn[e]);
    kb.e[e] = f2bf(k2 * cs[e] + k1 * sn[e]);
  }
  *reinterpret_cast<uint4*>(&QKV[base]) = qa.v;
  *reinterpret_cast<uint4*>(&QKV[base + 64]) = qb.v;
  *reinterpret_cast<uint4*>(&QKV[base + DMODEL]) = ka.v;
  *reinterpret_cast<uint4*>(&QKV[base + DMODEL + 64]) = kb.v;
}

// ---------------- V transpose: QKV V-columns -> Vt [2048][S] ----------------
__global__ __launch_bounds__(256) void transpose_kernel(const ushort* __restrict__ Vr,
                                                        ushort* __restrict__ Vt) {
  __shared__ __align__(16) ushort tile[64 * 72];
  int tid = threadIdx.x;
  int s0 = blockIdx.x * 64, c0 = blockIdx.y * 64;
#pragma unroll
  for (int it = 0; it < 2; ++it) {
    int i = tid + it * 256;
    int r = i >> 3, c = i & 7;
    *reinterpret_cast<uint4*>(&tile[r * 72 + c * 8]) =
        *reinterpret_cast<const uint4*>(&Vr[(size_t)(s0 + r) * LDQ + c0 + c * 8]);
  }
  __syncthreads();
#pragma unroll
  for (int it = 0; it < 2; ++it) {
    int i = tid + it * 256;
    int cr = i >> 3, sc = i & 7;
    ushort tmp[8];
#pragma unroll
    for (int j = 0; j < 8; ++j) tmp[j] = tile[(sc * 8 + j) * 72 + cr];
    *reinterpret_cast<uint4*>(&Vt[(size_t)(c0 + cr) * S_LEN + s0 + sc * 8]) =
        *reinterpret_cast<uint4*>(tmp);
  }
}

// ---------------- Flash attention v12 (round-11 champion, unchanged) ----------------
__global__ __launch_bounds__(256, 2) void flash12_kernel(const ushort* __restrict__ QKV,
                                                         const ushort* __restrict__ Vt,
                                                         ushort* __restrict__ Oh) {
  __shared__ __align__(16) ushort Kt[2][64 * 128];
  __shared__ __align__(16) ushort Vs[2][128 * 64];
  const int tid = threadIdx.x;             // 0..255
  const int wave = tid >> 6, lane = tid & 63;
  const int lg = lane >> 4, lm = lane & 15;
  const int id = blockIdx.y * gridDim.x + blockIdx.x;  // 0..511
  const int o = (id & 7) * 64 + (id >> 3);             // XCD swizzle (512 = 8*64)
  const int h = o >> 5;
  const int q0 = (o & 31) * 128;

  bf16x8 qh[2][4];
#pragma unroll
  for (int t2 = 0; t2 < 2; ++t2) {
    int qrow = q0 + wave * 32 + t2 * 16 + lm;
#pragma unroll
    for (int kc = 0; kc < 4; ++kc)
      qh[t2][kc] = *reinterpret_cast<const bf16x8*>(
          &QKV[(size_t)qrow * LDQ + h * HEADDIM + kc * 32 + lg * 8]);
  }

  bf16x8 ones;
#pragma unroll
  for (int i = 0; i < 8; ++i) ones[i] = (short)0x3f80;  // bf16 1.0

  auto rho = [](int s) {
    return 32 * ((s >> 4) & 1) + 8 * ((s >> 2) & 3) + 4 * (s >> 5) + (s & 3);
  };
  const ushort* Kb = QKV + DMODEL;  // K columns
  const ushort* pK[4];
  const ushort* pV[4];
  int lbs[4];
#pragma unroll
  for (int k = 0; k < 4; ++k) {
    int ci = k * 256 + wave * 64 + lane;
    int ks = ci >> 4;
    int kcc = (ci & 15) ^ (ks & 7);
    pK[k] = Kb + (size_t)rho(ks) * LDQ + h * HEADDIM + kcc * 8;
    int vd = ci >> 3;
    int vcc = (ci & 7) ^ (vd & 7);
    pV[k] = Vt + (size_t)(h * HEADDIM + vd) * S_LEN + vcc * 8;
    lbs[k] = (k * 256 + wave * 64) * 8;
  }

  f32x4 oacc[2][8] = {};
  f32x4 osum[2] = {};
  float mrun[2];
#pragma unroll
  for (int t2 = 0; t2 < 2; ++t2) mrun[t2] = -3.0e38f;

#pragma unroll
  for (int k = 0; k < 4; ++k) {
    gload16(pK[k], &Kt[0][lbs[k]]);
    gload16(pV[k], &Vs[0][lbs[k]]);
  }
  __syncthreads();

  for (int t = 0; t < S_LEN / 64; ++t) {
    const int cur = t & 1;
    if (t < S_LEN / 64 - 1) {
      const size_t koff = (size_t)(t + 1) * 64;
#pragma unroll
      for (int k = 0; k < 4; ++k) {
        gload16(pK[k] + koff * LDQ, &Kt[cur ^ 1][lbs[k]]);
        gload16(pV[k] + koff, &Vs[cur ^ 1][lbs[k]]);
      }
    }
    const ushort* Kc = &Kt[cur][0];
    const ushort* Vc = &Vs[cur][0];

    // QK^T swapped
    f32x4 st[2][4] = {};
    __builtin_amdgcn_s_setprio(1);
#pragma unroll
    for (int nf = 0; nf < 4; ++nf)
#pragma unroll
      for (int kc = 0; kc < 4; ++kc) {
        int pc = (kc * 4 + lg) ^ (lm & 7);
        bf16x8 kfrag = *reinterpret_cast<const bf16x8*>(&Kc[(nf * 16 + lm) * 128 + pc * 8]);
        st[0][nf] = __builtin_amdgcn_mfma_f32_16x16x32_bf16(kfrag, qh[0][kc], st[0][nf], 0, 0, 0);
        st[1][nf] = __builtin_amdgcn_mfma_f32_16x16x32_bf16(kfrag, qh[1][kc], st[1][nf], 0, 0, 0);
      }
    __builtin_amdgcn_s_setprio(0);

    // row max
    float m16[2];
#pragma unroll
    for (int t2 = 0; t2 < 2; ++t2) {
      float m = fmaxf(st[t2][0][0], st[t2][0][1]);
      m = fmaxf(fmaxf(m, st[t2][0][2]), st[t2][0][3]);
      m = fmaxf(fmaxf(m, st[t2][1][0]), st[t2][1][1]);
      m = fmaxf(fmaxf(m, st[t2][1][2]), st[t2][1][3]);
      m = fmaxf(fmaxf(m, st[t2][2][0]), st[t2][2][1]);
      m = fmaxf(fmaxf(m, st[t2][2][2]), st[t2][2][3]);
      m = fmaxf(fmaxf(m, st[t2][3][0]), st[t2][3][1]);
      m = fmaxf(fmaxf(m, st[t2][3][2]), st[t2][3][3]);
      m = fmaxf(m, __shfl_xor(m, 16));
      m = fmaxf(m, __shfl_xor(m, 32));
      m16[t2] = m;
    }

    // defer-max rescale (exp2 domain, thr 11.5 ~= 8*log2e)
    bool grow = (m16[0] > mrun[0] + 11.5f) || (m16[1] > mrun[1] + 11.5f);
    if (__any(grow)) {
#pragma unroll
      for (int t2 = 0; t2 < 2; ++t2) {
        float mn = fmaxf(mrun[t2], m16[t2]);
        float scl = fexp2(mrun[t2] - mn);
        mrun[t2] = mn;
        float sj[4];
#pragma unroll
        for (int j = 0; j < 4; ++j) sj[j] = __shfl(scl, lg * 4 + j);
#pragma unroll
        for (int j = 0; j < 4; ++j) osum[t2][j] *= sj[j];
#pragma unroll
        for (int nb = 0; nb < 8; ++nb)
#pragma unroll
          for (int j = 0; j < 4; ++j) oacc[t2][nb][j] *= sj[j];
      }
    }

    // P = exp2(S2 - m2) via raw v_exp_f32
#pragma unroll
    for (int t2 = 0; t2 < 2; ++t2)
#pragma unroll
      for (int nf = 0; nf < 4; ++nf)
#pragma unroll
        for (int j = 0; j < 4; ++j)
          st[t2][nf][j] = fexp2(st[t2][nf][j] - mrun[t2]);

    // pack PV A-frags
    bf16x8 pa[2][2];
#pragma unroll
    for (int t2 = 0; t2 < 2; ++t2)
#pragma unroll
      for (int kk = 0; kk < 2; ++kk) {
        union { unsigned int u[4]; bf16x8 v; } w_;
        w_.u[0] = cvtpk(st[t2][kk][0], st[t2][kk][1]);
        w_.u[1] = cvtpk(st[t2][kk][2], st[t2][kk][3]);
        w_.u[2] = cvtpk(st[t2][2 + kk][0], st[t2][2 + kk][1]);
        w_.u[3] = cvtpk(st[t2][2 + kk][2], st[t2][2 + kk][3]);
        pa[t2][kk] = w_.v;
      }

    // PV + row-sum via ones-MFMA
    __builtin_amdgcn_s_setprio(1);
#pragma unroll
    for (int t2 = 0; t2 < 2; ++t2) {
      osum[t2] = __builtin_amdgcn_mfma_f32_16x16x32_bf16(pa[t2][0], ones, osum[t2], 0, 0, 0);
      osum[t2] = __builtin_amdgcn_mfma_f32_16x16x32_bf16(pa[t2][1], ones, osum[t2], 0, 0, 0);
    }
#pragma unroll
    for (int nb = 0; nb < 8; ++nb)
#pragma unroll
      for (int kk = 0; kk < 2; ++kk) {
        int pc = (kk * 4 + lg) ^ (lm & 7);
        bf16x8 vfrag = *reinterpret_cast<const bf16x8*>(&Vc[(nb * 16 + lm) * 64 + pc * 8]);
        oacc[0][nb] = __builtin_amdgcn_mfma_f32_16x16x32_bf16(pa[0][kk], vfrag, oacc[0][nb], 0, 0, 0);
        oacc[1][nb] = __builtin_amdgcn_mfma_f32_16x16x32_bf16(pa[1][kk], vfrag, oacc[1][nb], 0, 0, 0);
      }
    __builtin_amdgcn_s_setprio(0);

    __syncthreads();
  }

  // epilogue: single bf16 O
#pragma unroll
  for (int t2 = 0; t2 < 2; ++t2) {
    float linv[4];
#pragma unroll
    for (int j = 0; j < 4; ++j) linv[j] = 1.0f / osum[t2][j];
#pragma unroll
    for (int nb = 0; nb < 8; ++nb)
#pragma unroll
      for (int j = 0; j < 4; ++j) {
        int row = q0 + wave * 32 + t2 * 16 + lg * 4 + j;
        int col = h * HEADDIM + nb * 16 + lm;
        Oh[(size_t)row * DMODEL + col] = f2bf(oacc[t2][nb][j] * linv[j]);
      }
  }
}

extern "C" void kernel_launch(void* const* d_in, const int* in_sizes, int n_in,
                              void* d_out, int out_size, void* d_ws, size_t ws_size,
                              hipStream_t stream) {
  (void)in_sizes; (void)n_in; (void)out_size; (void)ws_size;
  const float* X  = (const float*)d_in[0];
  const float* Wq = (const float*)d_in[1];
  const float* Wk = (const float*)d_in[2];
  const float* Wv = (const float*)d_in[3];
  const float* Wo = (const float*)d_in[4];
  const int* pos  = (const int*)d_in[5];
  float* out = (float*)d_out;

  ushort* wb = (ushort*)d_ws;
  const size_t SD = (size_t)S_LEN * DMODEL;       // 8388608 elements
  const size_t DD = (size_t)DMODEL * DMODEL;      // 4194304 elements

  ushort* Xh   = wb;                 // slot0
  ushort* QKV  = wb + 2 * SD;        // slots 2-4: [4096][6144]
  ushort* Vt   = wb + 5 * SD;        // slot5: [2048][4096]
  ushort* W0h  = wb + 6 * SD;        // Wo bf16
  ushort* Wqkv = wb + 7 * SD;        // [6144][2048]
  float* cosT  = (float*)(wb + 9 * SD);
  float* sinT  = cosT + (size_t)S_LEN * 64;
  ushort* OhB  = Wqkv;               // reuse after QKV GEMM done

  rope_table_kernel<<<S_LEN * 64 / 256, 256, 0, stream>>>(cosT, sinT);
  convert_kernel<<<SD / 1024, 256, 0, stream>>>(X, Xh);
  prep_weights<<<dim3(DD / 1024, 4), 256, 0, stream>>>(Wq, Wk, Wv, Wo, Wqkv, W0h);

  gemm_qkv<<<dim3(LDQ / 128, S_LEN / 128), 256, 0, stream>>>(Xh, Wqkv, QKV, S_LEN, LDQ, DMODEL);

  rope2_kernel<<<(S_LEN * 1024 / 8) / 256, 256, 0, stream>>>(QKV, pos, cosT, sinT);
  transpose_kernel<<<dim3(S_LEN / 64, DMODEL / 64), 256, 0, stream>>>(QKV + 2 * DMODEL, Vt);

  flash12_kernel<<<dim3(32, 16), 256, 0, stream>>>(QKV, Vt, OhB);

  dim3 gemmGrid(DMODEL / 128, S_LEN / 128);
  gemm1o64<<<gemmGrid, 256, 0, stream>>>(OhB, W0h, out, S_LEN, DMODEL, DMODEL);
}

// Round 14
// 339.865 us; speedup vs baseline: 1.4680x; 1.0018x over previous
//
#include <hip/hip_runtime.h>
#include <hip/hip_bf16.h>

#define S_LEN 4096
#define DMODEL 2048
#define NHEADS 16
#define HEADDIM 128
#define LDQ 6144  // stride of fused QKV buffer

typedef __attribute__((ext_vector_type(8))) short bf16x8;
typedef __attribute__((ext_vector_type(4))) float f32x4;

__device__ __forceinline__ float bf2f(ushort u) {
  union { unsigned int i; float f; } x; x.i = ((unsigned int)u) << 16; return x.f;
}
__device__ __forceinline__ ushort f2bf(float f) {
  union { float f; unsigned int i; } x; x.f = f;
  unsigned int u = x.i;
  unsigned int r = u + 0x7fffu + ((u >> 16) & 1u);
  return (ushort)(r >> 16);
}
__device__ __forceinline__ unsigned int cvtpk(float a, float b) {
  unsigned int r;
  asm("v_cvt_pk_bf16_f32 %0, %1, %2" : "=v"(r) : "v"(a), "v"(b));
  return r;
}
// fast hardware exp2 (v_exp_f32 IS 2^x); bypasses ocml's precise path
__device__ __forceinline__ float fexp2(float x) {
  float r;
  asm("v_exp_f32 %0, %1" : "=v"(r) : "v"(x));
  return r;
}

__device__ __forceinline__ void gload16(const ushort* g, ushort* l) {
  __builtin_amdgcn_global_load_lds(
      (const __attribute__((address_space(1))) unsigned int*)g,
      (__attribute__((address_space(3))) unsigned int*)l, 16, 0, 0);
}

// ---------------- RoPE cos/sin table ----------------
__global__ __launch_bounds__(256) void rope_table_kernel(float* __restrict__ cosT,
                                                         float* __restrict__ sinT) {
  int idx = blockIdx.x * 256 + threadIdx.x;
  int t = idx >> 6, j = idx & 63;
  float expo = (float)(2 * j) / 128.0f;
  float inv = 1.0f / powf(10000.0f, expo);
  float f = (float)t * inv;
  cosT[idx] = cosf(f);
  sinT[idx] = sinf(f);
}

// ---------------- fp32 -> bf16 (RNE) convert ----------------
__global__ __launch_bounds__(256) void convert_kernel(const float* __restrict__ in,
                                                      ushort* __restrict__ hi) {
  int i = (blockIdx.x * 256 + threadIdx.x) * 4;
  float4 v = *reinterpret_cast<const float4*>(&in[i]);
  ushort4 h;
  h.x = f2bf(v.x); h.y = f2bf(v.y); h.z = f2bf(v.z); h.w = f2bf(v.w);
  *reinterpret_cast<ushort4*>(&hi[i]) = h;
}

// ---------------- weight prep: Wq/Wk/Wv -> packed bf16 [6144][2048]; Wo -> bf16 ----------------
__global__ __launch_bounds__(256) void prep_weights(const float* __restrict__ Wq,
                                                    const float* __restrict__ Wk,
                                                    const float* __restrict__ Wv,
                                                    const float* __restrict__ Wo,
                                                    ushort* __restrict__ Wqkv,
                                                    ushort* __restrict__ Woh) {
  int i = (blockIdx.x * 256 + threadIdx.x) * 4;
  int which = blockIdx.y;
  const float* src = (which == 0) ? Wq : (which == 1) ? Wk : (which == 2) ? Wv : Wo;
  ushort* dst = (which == 3) ? Woh : (Wqkv + (size_t)which * DMODEL * DMODEL);
  float4 v = *reinterpret_cast<const float4*>(&src[i]);
  ushort4 h;
  h.x = f2bf(v.x); h.y = f2bf(v.y); h.z = f2bf(v.z); h.w = f2bf(v.w);
  *reinterpret_cast<ushort4*>(&dst[i]) = h;
}

// ---------------- fused QKV GEMM: QKV = Xh * Wqkv^T, BK=64, 128x128 tile ----------------
__global__ __launch_bounds__(256) void gemm_qkv(const ushort* __restrict__ Ah_,
                                                const ushort* __restrict__ Bh_,
                                                ushort* __restrict__ Cout,
                                                int M, int N, int K) {
  __shared__ __align__(16) ushort sAh[128 * 64], sBh[128 * 64];
  const int tid = threadIdx.x;
  const int wave = tid >> 6, lane = tid & 63;
  const int lg = lane >> 4, lm = lane & 15;
  const int nwg = gridDim.x * gridDim.y;
  const int id = blockIdx.y * gridDim.x + blockIdx.x;
  const int cpx = nwg >> 3;
  const int swz = (id & 7) * cpx + (id >> 3);
  const int nbx = N >> 7;
  const int m0 = (swz / nbx) * 128, n0 = (swz % nbx) * 128;
  const int wm = (wave >> 1) * 64, wn = (wave & 1) * 64;
  f32x4 acc[4][4] = {};

  int srow[4], scc[4], lbs[4];
#pragma unroll
  for (int it = 0; it < 4; ++it) {
    int ci = it * 256 + wave * 64 + lane;
    srow[it] = ci >> 3;
    scc[it] = (ci & 7) ^ (srow[it] & 7);
    lbs[it] = (it * 256 + wave * 64) * 8;
  }

  for (int k0 = 0; k0 < K; k0 += 64) {
    __syncthreads();
#pragma unroll
    for (int it = 0; it < 4; ++it) {
      size_t ga = (size_t)(m0 + srow[it]) * K + k0 + scc[it] * 8;
      size_t gb = (size_t)(n0 + srow[it]) * K + k0 + scc[it] * 8;
      gload16(&Ah_[ga], &sAh[lbs[it]]);
      gload16(&Bh_[gb], &sBh[lbs[it]]);
    }
    __syncthreads();
    bf16x8 ah[4][2], bh[4][2];
#pragma unroll
    for (int t = 0; t < 4; ++t)
#pragma unroll
      for (int kc = 0; kc < 2; ++kc) {
        int Ra = wm + t * 16 + lm;
        int Rb = wn + t * 16 + lm;
        int pa_ = ((kc * 4 + lg) ^ (Ra & 7)) * 8;
        int pb_ = ((kc * 4 + lg) ^ (Rb & 7)) * 8;
        ah[t][kc] = *reinterpret_cast<const bf16x8*>(&sAh[Ra * 64 + pa_]);
        bh[t][kc] = *reinterpret_cast<const bf16x8*>(&sBh[Rb * 64 + pb_]);
      }
#pragma unroll
    for (int kc = 0; kc < 2; ++kc)
#pragma unroll
      for (int mi = 0; mi < 4; ++mi)
#pragma unroll
        for (int ni = 0; ni < 4; ++ni)
          acc[mi][ni] = __builtin_amdgcn_mfma_f32_16x16x32_bf16(ah[mi][kc], bh[ni][kc], acc[mi][ni], 0, 0, 0);
  }
#pragma unroll
  for (int mi = 0; mi < 4; ++mi)
#pragma unroll
    for (int ni = 0; ni < 4; ++ni)
#pragma unroll
      for (int j = 0; j < 4; ++j) {
        int row = m0 + wm + mi * 16 + lg * 4 + j;
        int col = n0 + wn + ni * 16 + lm;
        Cout[(size_t)row * N + col] = f2bf(acc[mi][ni][j]);
      }
}

// ---------------- 1-term final GEMM, BK=64 structure: out = Oh * Woh^T (f32 out) ----------------
__global__ __launch_bounds__(256) void gemm1o64(const ushort* __restrict__ Ah_,
                                                const ushort* __restrict__ Bh_,
                                                float* __restrict__ Cout,
                                                int M, int N, int K) {
  __shared__ __align__(16) ushort sAh[128 * 64], sBh[128 * 64];
  const int tid = threadIdx.x;
  const int wave = tid >> 6, lane = tid & 63;
  const int lg = lane >> 4, lm = lane & 15;
  const int nwg = gridDim.x * gridDim.y;
  const int id = blockIdx.y * gridDim.x + blockIdx.x;
  const int cpx = nwg >> 3;
  const int swz = (id & 7) * cpx + (id >> 3);
  const int nbx = N >> 7;
  const int m0 = (swz / nbx) * 128, n0 = (swz % nbx) * 128;
  const int wm = (wave >> 1) * 64, wn = (wave & 1) * 64;
  f32x4 acc[4][4] = {};

  int srow[4], scc[4], lbs[4];
#pragma unroll
  for (int it = 0; it < 4; ++it) {
    int ci = it * 256 + wave * 64 + lane;
    srow[it] = ci >> 3;
    scc[it] = (ci & 7) ^ (srow[it] & 7);
    lbs[it] = (it * 256 + wave * 64) * 8;
  }

  for (int k0 = 0; k0 < K; k0 += 64) {
    __syncthreads();
#pragma unroll
    for (int it = 0; it < 4; ++it) {
      size_t ga = (size_t)(m0 + srow[it]) * K + k0 + scc[it] * 8;
      size_t gb = (size_t)(n0 + srow[it]) * K + k0 + scc[it] * 8;
      gload16(&Ah_[ga], &sAh[lbs[it]]);
      gload16(&Bh_[gb], &sBh[lbs[it]]);
    }
    __syncthreads();
    bf16x8 ah[4][2], bh[4][2];
#pragma unroll
    for (int t = 0; t < 4; ++t)
#pragma unroll
      for (int kc = 0; kc < 2; ++kc) {
        int Ra = wm + t * 16 + lm;
        int Rb = wn + t * 16 + lm;
        int pa_ = ((kc * 4 + lg) ^ (Ra & 7)) * 8;
        int pb_ = ((kc * 4 + lg) ^ (Rb & 7)) * 8;
        ah[t][kc] = *reinterpret_cast<const bf16x8*>(&sAh[Ra * 64 + pa_]);
        bh[t][kc] = *reinterpret_cast<const bf16x8*>(&sBh[Rb * 64 + pb_]);
      }
#pragma unroll
    for (int kc = 0; kc < 2; ++kc)
#pragma unroll
      for (int mi = 0; mi < 4; ++mi)
#pragma unroll
        for (int ni = 0; ni < 4; ++ni)
          acc[mi][ni] = __builtin_amdgcn_mfma_f32_16x16x32_bf16(ah[mi][kc], bh[ni][kc], acc[mi][ni], 0, 0, 0);
  }
#pragma unroll
  for (int mi = 0; mi < 4; ++mi)
#pragma unroll
    for (int ni = 0; ni < 4; ++ni)
#pragma unroll
      for (int j = 0; j < 4; ++j) {
        int row = m0 + wm + mi * 16 + lg * 4 + j;
        int col = n0 + wn + ni * 16 + lm;
        Cout[(size_t)row * N + col] = acc[mi][ni][j];
      }
}

// ---------------- RoPE in-place on QKV buffer (vectorized x8): Q scaled by log2e/sqrt(HD) ----------------
__global__ __launch_bounds__(256) void rope2_kernel(ushort* __restrict__ QKV,
                                                    const int* __restrict__ pos,
                                                    const float* __restrict__ cosT,
                                                    const float* __restrict__ sinT) {
  int t = blockIdx.x * 256 + threadIdx.x;  // S*1024/8 threads
  int j0 = (t & 7) * 8;
  int hh = (t >> 3) & 15;
  int s = t >> 7;
  int p = pos[s];
  float cs[8], sn[8];
  *reinterpret_cast<float4*>(&cs[0]) = *reinterpret_cast<const float4*>(&cosT[p * 64 + j0]);
  *reinterpret_cast<float4*>(&cs[4]) = *reinterpret_cast<const float4*>(&cosT[p * 64 + j0 + 4]);
  *reinterpret_cast<float4*>(&sn[0]) = *reinterpret_cast<const float4*>(&sinT[p * 64 + j0]);
  *reinterpret_cast<float4*>(&sn[4]) = *reinterpret_cast<const float4*>(&sinT[p * 64 + j0 + 4]);
  size_t base = (size_t)s * LDQ + hh * HEADDIM + j0;
  union u8 { uint4 v; ushort e[8]; };
  u8 qa, qb, ka, kb;
  qa.v = *reinterpret_cast<const uint4*>(&QKV[base]);
  qb.v = *reinterpret_cast<const uint4*>(&QKV[base + 64]);
  ka.v = *reinterpret_cast<const uint4*>(&QKV[base + DMODEL]);
  kb.v = *reinterpret_cast<const uint4*>(&QKV[base + DMODEL + 64]);
  const float scl = 0.12751742f;  // log2(e)/sqrt(128)
#pragma unroll
  for (int e = 0; e < 8; ++e) {
    float q1 = bf2f(qa.e[e]), q2 = bf2f(qb.e[e]);
    float k1 = bf2f(ka.e[e]), k2 = bf2f(kb.e[e]);
    qa.e[e] = f2bf((q1 * cs[e] - q2 * sn[e]) * scl);
    qb.e[e] = f2bf((q2 * cs[e] + q1 * sn[e]) * scl);
    ka.e[e] = f2bf(k1 * cs[e] - k2 * sn[e]);
    kb.e[e] = f2bf(k2 * cs[e] + k1 * sn[e]);
  }
  *reinterpret_cast<uint4*>(&QKV[base]) = qa.v;
  *reinterpret_cast<uint4*>(&QKV[base + 64]) = qb.v;
  *reinterpret_cast<uint4*>(&QKV[base + DMODEL]) = ka.v;
  *reinterpret_cast<uint4*>(&QKV[base + DMODEL + 64]) = kb.v;
}

// ---------------- V transpose: QKV V-columns -> Vt [2048][S] ----------------
__global__ __launch_bounds__(256) void transpose_kernel(const ushort* __restrict__ Vr,
                                                        ushort* __restrict__ Vt) {
  __shared__ __align__(16) ushort tile[64 * 72];
  int tid = threadIdx.x;
  int s0 = blockIdx.x * 64, c0 = blockIdx.y * 64;
#pragma unroll
  for (int it = 0; it < 2; ++it) {
    int i = tid + it * 256;
    int r = i >> 3, c = i & 7;
    *reinterpret_cast<uint4*>(&tile[r * 72 + c * 8]) =
        *reinterpret_cast<const uint4*>(&Vr[(size_t)(s0 + r) * LDQ + c0 + c * 8]);
  }
  __syncthreads();
#pragma unroll
  for (int it = 0; it < 2; ++it) {
    int i = tid + it * 256;
    int cr = i >> 3, sc = i & 7;
    ushort tmp[8];
#pragma unroll
    for (int j = 0; j < 8; ++j) tmp[j] = tile[(sc * 8 + j) * 72 + cr];
    *reinterpret_cast<uint4*>(&Vt[(size_t)(c0 + cr) * S_LEN + s0 + sc * 8]) =
        *reinterpret_cast<uint4*>(tmp);
  }
}

// ---------------- Flash v14 = flash12 + T15 double-pipeline ----------------
// Iteration t: [softmax(t)+PV(t) on st_cur] -> barrier -> stage(t+2) -> QK^T(t+1)->st_next.
// QK^T(t+1) MFMAs are issued before softmax VALU of the NEXT iteration consumes them,
// so MFMA and VALU overlap within each wave. Buffers: K/V double-buffered as four
// DISTINCT __shared__ arrays (static references; no alias-forced waits).
// One vmcnt drain per tile (at __syncthreads), loads span a full tile of compute.
#define FTILE(STC, STN, VCUR, KWB, VWB, KRB, T)                                           \
  {                                                                                       \
    float m16[2];                                                                         \
    _Pragma("unroll") for (int t2 = 0; t2 < 2; ++t2) {                                    \
      float m = fmaxf(STC[t2][0][0], STC[t2][0][1]);                                      \
      m = fmaxf(fmaxf(m, STC[t2][0][2]), STC[t2][0][3]);                                  \
      m = fmaxf(fmaxf(m, STC[t2][1][0]), STC[t2][1][1]);                                  \
      m = fmaxf(fmaxf(m, STC[t2][1][2]), STC[t2][1][3]);                                  \
      m = fmaxf(fmaxf(m, STC[t2][2][0]), STC[t2][2][1]);                                  \
      m = fmaxf(fmaxf(m, STC[t2][2][2]), STC[t2][2][3]);                                  \
      m = fmaxf(fmaxf(m, STC[t2][3][0]), STC[t2][3][1]);                                  \
      m = fmaxf(fmaxf(m, STC[t2][3][2]), STC[t2][3][3]);                                  \
      m = fmaxf(m, __shfl_xor(m, 16));                                                    \
      m = fmaxf(m, __shfl_xor(m, 32));                                                    \
      m16[t2] = m;                                                                        \
    }                                                                                     \
    bool grow = (m16[0] > mrun[0] + 11.5f) || (m16[1] > mrun[1] + 11.5f);                 \
    if (__any(grow)) {                                                                    \
      _Pragma("unroll") for (int t2 = 0; t2 < 2; ++t2) {                                  \
        float mn = fmaxf(mrun[t2], m16[t2]);                                              \
        float scl = fexp2(mrun[t2] - mn);                                                 \
        mrun[t2] = mn;                                                                    \
        float sj[4];                                                                      \
        _Pragma("unroll") for (int j = 0; j < 4; ++j) sj[j] = __shfl(scl, lg * 4 + j);    \
        _Pragma("unroll") for (int j = 0; j < 4; ++j) osum[t2][j] *= sj[j];               \
        _Pragma("unroll") for (int nb = 0; nb < 8; ++nb)                                  \
            _Pragma("unroll") for (int j = 0; j < 4; ++j) oacc[t2][nb][j] *= sj[j];       \
      }                                                                                   \
    }                                                                                     \
    _Pragma("unroll") for (int t2 = 0; t2 < 2; ++t2)                                      \
        _Pragma("unroll") for (int nf = 0; nf < 4; ++nf)                                  \
            _Pragma("unroll") for (int j = 0; j < 4; ++j)                                 \
                STC[t2][nf][j] = fexp2(STC[t2][nf][j] - mrun[t2]);                        \
    bf16x8 pa[2][2];                                                                      \
    _Pragma("unroll") for (int t2 = 0; t2 < 2; ++t2)                                      \
        _Pragma("unroll") for (int kk = 0; kk < 2; ++kk) {                                \
      union { unsigned int u[4]; bf16x8 v; } w_;                                          \
      w_.u[0] = cvtpk(STC[t2][kk][0], STC[t2][kk][1]);                                    \
      w_.u[1] = cvtpk(STC[t2][kk][2], STC[t2][kk][3]);                                    \
      w_.u[2] = cvtpk(STC[t2][2 + kk][0], STC[t2][2 + kk][1]);                            \
      w_.u[3] = cvtpk(STC[t2][2 + kk][2], STC[t2][2 + kk][3]);                            \
      pa[t2][kk] = w_.v;                                                                  \
    }                                                                                     \
    __builtin_amdgcn_s_setprio(1);                                                        \
    _Pragma("unroll") for (int t2 = 0; t2 < 2; ++t2) {                                    \
      osum[t2] = __builtin_amdgcn_mfma_f32_16x16x32_bf16(pa[t2][0], ones, osum[t2], 0, 0, 0); \
      osum[t2] = __builtin_amdgcn_mfma_f32_16x16x32_bf16(pa[t2][1], ones, osum[t2], 0, 0, 0); \
    }                                                                                     \
    _Pragma("unroll") for (int nb = 0; nb < 8; ++nb)                                      \
        _Pragma("unroll") for (int kk = 0; kk < 2; ++kk) {                                \
      int pc = (kk * 4 + lg) ^ (lm & 7);                                                  \
      bf16x8 vfrag = *reinterpret_cast<const bf16x8*>(&VCUR[(nb * 16 + lm) * 64 + pc * 8]); \
      oacc[0][nb] = __builtin_amdgcn_mfma_f32_16x16x32_bf16(pa[0][kk], vfrag, oacc[0][nb], 0, 0, 0); \
      oacc[1][nb] = __builtin_amdgcn_mfma_f32_16x16x32_bf16(pa[1][kk], vfrag, oacc[1][nb], 0, 0, 0); \
    }                                                                                     \
    __builtin_amdgcn_s_setprio(0);                                                        \
    __syncthreads();                                                                      \
    if ((T) + 2 < 64) {                                                                   \
      const size_t ko_ = (size_t)((T) + 2) * 64;                                          \
      _Pragma("unroll") for (int k = 0; k < 4; ++k) {                                     \
        gload16(pK[k] + ko_ * LDQ, &KWB[lbs[k]]);                                         \
        gload16(pV[k] + ko_, &VWB[lbs[k]]);                                               \
      }                                                                                   \
    }                                                                                     \
    if ((T) + 1 < 64) {                                                                   \
      _Pragma("unroll") for (int t2 = 0; t2 < 2; ++t2)                                    \
          _Pragma("unroll") for (int nf = 0; nf < 4; ++nf) STN[t2][nf] = fzero;           \
      __builtin_amdgcn_s_setprio(1);                                                      \
      _Pragma("unroll") for (int nf = 0; nf < 4; ++nf)                                    \
          _Pragma("unroll") for (int kc = 0; kc < 4; ++kc) {                              \
        int pc = (kc * 4 + lg) ^ (lm & 7);                                                \
        bf16x8 kfrag = *reinterpret_cast<const bf16x8*>(&KRB[(nf * 16 + lm) * 128 + pc * 8]); \
        STN[0][nf] = __builtin_amdgcn_mfma_f32_16x16x32_bf16(kfrag, qh[0][kc], STN[0][nf], 0, 0, 0); \
        STN[1][nf] = __builtin_amdgcn_mfma_f32_16x16x32_bf16(kfrag, qh[1][kc], STN[1][nf], 0, 0, 0); \
      }                                                                                   \
      __builtin_amdgcn_s_setprio(0);                                                      \
    }                                                                                     \
  }

__global__ __launch_bounds__(256, 2) void flash14_kernel(const ushort* __restrict__ QKV,
                                                         const ushort* __restrict__ Vt,
                                                         ushort* __restrict__ Oh) {
  __shared__ __align__(16) ushort KtA[64 * 128];
  __shared__ __align__(16) ushort KtB[64 * 128];
  __shared__ __align__(16) ushort VsA[128 * 64];
  __shared__ __align__(16) ushort VsB[128 * 64];
  const int tid = threadIdx.x;             // 0..255
  const int wave = tid >> 6, lane = tid & 63;
  const int lg = lane >> 4, lm = lane & 15;
  const int id = blockIdx.y * gridDim.x + blockIdx.x;  // 0..511
  const int o = (id & 7) * 64 + (id >> 3);             // XCD swizzle (512 = 8*64)
  const int h = o >> 5;
  const int q0 = (o & 31) * 128;
  const f32x4 fzero = {};

  bf16x8 qh[2][4];
#pragma unroll
  for (int t2 = 0; t2 < 2; ++t2) {
    int qrow = q0 + wave * 32 + t2 * 16 + lm;
#pragma unroll
    for (int kc = 0; kc < 4; ++kc)
      qh[t2][kc] = *reinterpret_cast<const bf16x8*>(
          &QKV[(size_t)qrow * LDQ + h * HEADDIM + kc * 32 + lg * 8]);
  }

  bf16x8 ones;
#pragma unroll
  for (int i = 0; i < 8; ++i) ones[i] = (short)0x3f80;  // bf16 1.0

  auto rho = [](int s) {
    return 32 * ((s >> 4) & 1) + 8 * ((s >> 2) & 3) + 4 * (s >> 5) + (s & 3);
  };
  const ushort* Kb = QKV + DMODEL;  // K columns
  const ushort* pK[4];
  const ushort* pV[4];
  int lbs[4];
#pragma unroll
  for (int k = 0; k < 4; ++k) {
    int ci = k * 256 + wave * 64 + lane;
    int ks = ci >> 4;
    int kcc = (ci & 15) ^ (ks & 7);
    pK[k] = Kb + (size_t)rho(ks) * LDQ + h * HEADDIM + kcc * 8;
    int vd = ci >> 3;
    int vcc = (ci & 7) ^ (vd & 7);
    pV[k] = Vt + (size_t)(h * HEADDIM + vd) * S_LEN + vcc * 8;
    lbs[k] = (k * 256 + wave * 64) * 8;
  }

  f32x4 oacc[2][8] = {};
  f32x4 osum[2] = {};
  float mrun[2];
#pragma unroll
  for (int t2 = 0; t2 < 2; ++t2) mrun[t2] = -3.0e38f;

  // prologue: stage tile 0 -> A buffers; drain; issue tile 1 -> B buffers; QK^T(0)
#pragma unroll
  for (int k = 0; k < 4; ++k) {
    gload16(pK[k], &KtA[lbs[k]]);
    gload16(pV[k], &VsA[lbs[k]]);
  }
  __syncthreads();
#pragma unroll
  for (int k = 0; k < 4; ++k) {
    gload16(pK[k] + (size_t)64 * LDQ, &KtB[lbs[k]]);
    gload16(pV[k] + 64, &VsB[lbs[k]]);
  }
  f32x4 stA[2][4], stB[2][4];
#pragma unroll
  for (int t2 = 0; t2 < 2; ++t2)
#pragma unroll
    for (int nf = 0; nf < 4; ++nf) stA[t2][nf] = fzero;
  __builtin_amdgcn_s_setprio(1);
#pragma unroll
  for (int nf = 0; nf < 4; ++nf)
#pragma unroll
    for (int kc = 0; kc < 4; ++kc) {
      int pc = (kc * 4 + lg) ^ (lm & 7);
      bf16x8 kfrag = *reinterpret_cast<const bf16x8*>(&KtA[(nf * 16 + lm) * 128 + pc * 8]);
      stA[0][nf] = __builtin_amdgcn_mfma_f32_16x16x32_bf16(kfrag, qh[0][kc], stA[0][nf], 0, 0, 0);
      stA[1][nf] = __builtin_amdgcn_mfma_f32_16x16x32_bf16(kfrag, qh[1][kc], stA[1][nf], 0, 0, 0);
    }
  __builtin_amdgcn_s_setprio(0);

  for (int tp = 0; tp < 32; ++tp) {
    const int t0 = 2 * tp;
    FTILE(stA, stB, VsA, KtA, VsA, KtB, t0)
    FTILE(stB, stA, VsB, KtB, VsB, KtA, t0 + 1)
  }

  // epilogue: single bf16 O
#pragma unroll
  for (int t2 = 0; t2 < 2; ++t2) {
    float linv[4];
#pragma unroll
    for (int j = 0; j < 4; ++j) linv[j] = 1.0f / osum[t2][j];
#pragma unroll
    for (int nb = 0; nb < 8; ++nb)
#pragma unroll
      for (int j = 0; j < 4; ++j) {
        int row = q0 + wave * 32 + t2 * 16 + lg * 4 + j;
        int col = h * HEADDIM + nb * 16 + lm;
        Oh[(size_t)row * DMODEL + col] = f2bf(oacc[t2][nb][j] * linv[j]);
      }
  }
}

extern "C" void kernel_launch(void* const* d_in, const int* in_sizes, int n_in,
                              void* d_out, int out_size, void* d_ws, size_t ws_size,
                              hipStream_t stream) {
  (void)in_sizes; (void)n_in; (void)out_size; (void)ws_size;
  const float* X  = (const float*)d_in[0];
  const float* Wq = (const float*)d_in[1];
  const float* Wk = (const float*)d_in[2];
  const float* Wv = (const float*)d_in[3];
  const float* Wo = (const float*)d_in[4];
  const int* pos  = (const int*)d_in[5];
  float* out = (float*)d_out;

  ushort* wb = (ushort*)d_ws;
  const size_t SD = (size_t)S_LEN * DMODEL;       // 8388608 elements
  const size_t DD = (size_t)DMODEL * DMODEL;      // 4194304 elements

  ushort* Xh   = wb;                 // slot0
  ushort* QKV  = wb + 2 * SD;        // slots 2-4: [4096][6144]
  ushort* Vt   = wb + 5 * SD;        // slot5: [2048][4096]
  ushort* W0h  = wb + 6 * SD;        // Wo bf16
  ushort* Wqkv = wb + 7 * SD;        // [6144][2048]
  float* cosT  = (float*)(wb + 9 * SD);
  float* sinT  = cosT + (size_t)S_LEN * 64;
  ushort* OhB  = Wqkv;               // reuse after QKV GEMM done

  rope_table_kernel<<<S_LEN * 64 / 256, 256, 0, stream>>>(cosT, sinT);
  convert_kernel<<<SD / 1024, 256, 0, stream>>>(X, Xh);
  prep_weights<<<dim3(DD / 1024, 4), 256, 0, stream>>>(Wq, Wk, Wv, Wo, Wqkv, W0h);

  gemm_qkv<<<dim3(LDQ / 128, S_LEN / 128), 256, 0, stream>>>(Xh, Wqkv, QKV, S_LEN, LDQ, DMODEL);

  rope2_kernel<<<(S_LEN * 1024 / 8) / 256, 256, 0, stream>>>(QKV, pos, cosT, sinT);
  transpose_kernel<<<dim3(S_LEN / 64, DMODEL / 64), 256, 0, stream>>>(QKV + 2 * DMODEL, Vt);

  flash14_kernel<<<dim3(32, 16), 256, 0, stream>>>(QKV, Vt, OhB);

  dim3 gemmGrid(DMODEL / 128, S_LEN / 128);
  gemm1o64<<<gemmGrid, 256, 0, stream>>>(OhB, W0h, out, S_LEN, DMODEL, DMODEL);
}

// Round 15
// 335.161 us; speedup vs baseline: 1.4886x; 1.0140x over previous
//
#include <hip/hip_runtime.h>
#include <hip/hip_bf16.h>

#define S_LEN 4096
#define DMODEL 2048
#define NHEADS 16
#define HEADDIM 128
#define LDQ 6144  // stride of fused QKV buffer

typedef __attribute__((ext_vector_type(8))) short bf16x8;
typedef __attribute__((ext_vector_type(4))) float f32x4;

__device__ __forceinline__ float bf2f(ushort u) {
  union { unsigned int i; float f; } x; x.i = ((unsigned int)u) << 16; return x.f;
}
__device__ __forceinline__ ushort f2bf(float f) {
  union { float f; unsigned int i; } x; x.f = f;
  unsigned int u = x.i;
  unsigned int r = u + 0x7fffu + ((u >> 16) & 1u);
  return (ushort)(r >> 16);
}
__device__ __forceinline__ unsigned int cvtpk(float a, float b) {
  unsigned int r;
  asm("v_cvt_pk_bf16_f32 %0, %1, %2" : "=v"(r) : "v"(a), "v"(b));
  return r;
}
// fast hardware exp2 (v_exp_f32 IS 2^x); bypasses ocml's precise path
__device__ __forceinline__ float fexp2(float x) {
  float r;
  asm("v_exp_f32 %0, %1" : "=v"(r) : "v"(x));
  return r;
}

__device__ __forceinline__ void gload16(const ushort* g, ushort* l) {
  __builtin_amdgcn_global_load_lds(
      (const __attribute__((address_space(1))) unsigned int*)g,
      (__attribute__((address_space(3))) unsigned int*)l, 16, 0, 0);
}

// ---------------- fused prep: rope table + X convert + weight prep, one launch ----------------
__global__ __launch_bounds__(256) void prep_all(const float* __restrict__ X,
                                                const float* __restrict__ Wq,
                                                const float* __restrict__ Wk,
                                                const float* __restrict__ Wv,
                                                const float* __restrict__ Wo,
                                                ushort* __restrict__ Xh,
                                                ushort* __restrict__ Wqkv,
                                                ushort* __restrict__ Woh,
                                                float* __restrict__ cosT,
                                                float* __restrict__ sinT) {
  int which = blockIdx.y;
  if (which < 4) {  // weights: 4096 blocks each
    int i = (blockIdx.x * 256 + threadIdx.x) * 4;
    const float* src = (which == 0) ? Wq : (which == 1) ? Wk : (which == 2) ? Wv : Wo;
    ushort* dst = (which == 3) ? Woh : (Wqkv + (size_t)which * DMODEL * DMODEL);
    float4 v = *reinterpret_cast<const float4*>(&src[i]);
    ushort4 h;
    h.x = f2bf(v.x); h.y = f2bf(v.y); h.z = f2bf(v.z); h.w = f2bf(v.w);
    *reinterpret_cast<ushort4*>(&dst[i]) = h;
  } else if (which < 6) {  // X: 2 x 4096 blocks
    int i = (((which - 4) * 4096 + blockIdx.x) * 256 + threadIdx.x) * 4;
    float4 v = *reinterpret_cast<const float4*>(&X[i]);
    ushort4 h;
    h.x = f2bf(v.x); h.y = f2bf(v.y); h.z = f2bf(v.z); h.w = f2bf(v.w);
    *reinterpret_cast<ushort4*>(&Xh[i]) = h;
  } else {  // rope table: first 1024 blocks
    if (blockIdx.x >= 1024) return;
    int idx = blockIdx.x * 256 + threadIdx.x;  // S*64
    int t = idx >> 6, j = idx & 63;
    float expo = (float)(2 * j) / 128.0f;
    float inv = 1.0f / powf(10000.0f, expo);
    float f = (float)t * inv;
    cosT[idx] = cosf(f);
    sinT[idx] = sinf(f);
  }
}

// ---------------- fused QKV GEMM: QKV = Xh * Wqkv^T, BK=64, 128x128 tile ----------------
__global__ __launch_bounds__(256) void gemm_qkv(const ushort* __restrict__ Ah_,
                                                const ushort* __restrict__ Bh_,
                                                ushort* __restrict__ Cout,
                                                int M, int N, int K) {
  __shared__ __align__(16) ushort sAh[128 * 64], sBh[128 * 64];
  const int tid = threadIdx.x;
  const int wave = tid >> 6, lane = tid & 63;
  const int lg = lane >> 4, lm = lane & 15;
  const int nwg = gridDim.x * gridDim.y;
  const int id = blockIdx.y * gridDim.x + blockIdx.x;
  const int cpx = nwg >> 3;
  const int swz = (id & 7) * cpx + (id >> 3);
  const int nbx = N >> 7;
  const int m0 = (swz / nbx) * 128, n0 = (swz % nbx) * 128;
  const int wm = (wave >> 1) * 64, wn = (wave & 1) * 64;
  f32x4 acc[4][4] = {};

  int srow[4], scc[4], lbs[4];
#pragma unroll
  for (int it = 0; it < 4; ++it) {
    int ci = it * 256 + wave * 64 + lane;
    srow[it] = ci >> 3;
    scc[it] = (ci & 7) ^ (srow[it] & 7);
    lbs[it] = (it * 256 + wave * 64) * 8;
  }

  for (int k0 = 0; k0 < K; k0 += 64) {
    __syncthreads();
#pragma unroll
    for (int it = 0; it < 4; ++it) {
      size_t ga = (size_t)(m0 + srow[it]) * K + k0 + scc[it] * 8;
      size_t gb = (size_t)(n0 + srow[it]) * K + k0 + scc[it] * 8;
      gload16(&Ah_[ga], &sAh[lbs[it]]);
      gload16(&Bh_[gb], &sBh[lbs[it]]);
    }
    __syncthreads();
    bf16x8 ah[4][2], bh[4][2];
#pragma unroll
    for (int t = 0; t < 4; ++t)
#pragma unroll
      for (int kc = 0; kc < 2; ++kc) {
        int Ra = wm + t * 16 + lm;
        int Rb = wn + t * 16 + lm;
        int pa_ = ((kc * 4 + lg) ^ (Ra & 7)) * 8;
        int pb_ = ((kc * 4 + lg) ^ (Rb & 7)) * 8;
        ah[t][kc] = *reinterpret_cast<const bf16x8*>(&sAh[Ra * 64 + pa_]);
        bh[t][kc] = *reinterpret_cast<const bf16x8*>(&sBh[Rb * 64 + pb_]);
      }
#pragma unroll
    for (int kc = 0; kc < 2; ++kc)
#pragma unroll
      for (int mi = 0; mi < 4; ++mi)
#pragma unroll
        for (int ni = 0; ni < 4; ++ni)
          acc[mi][ni] = __builtin_amdgcn_mfma_f32_16x16x32_bf16(ah[mi][kc], bh[ni][kc], acc[mi][ni], 0, 0, 0);
  }
#pragma unroll
  for (int mi = 0; mi < 4; ++mi)
#pragma unroll
    for (int ni = 0; ni < 4; ++ni)
#pragma unroll
      for (int j = 0; j < 4; ++j) {
        int row = m0 + wm + mi * 16 + lg * 4 + j;
        int col = n0 + wn + ni * 16 + lm;
        Cout[(size_t)row * N + col] = f2bf(acc[mi][ni][j]);
      }
}

// ---------------- 1-term final GEMM, BK=64 structure: out = Oh * Woh^T (f32 out) ----------------
__global__ __launch_bounds__(256) void gemm1o64(const ushort* __restrict__ Ah_,
                                                const ushort* __restrict__ Bh_,
                                                float* __restrict__ Cout,
                                                int M, int N, int K) {
  __shared__ __align__(16) ushort sAh[128 * 64], sBh[128 * 64];
  const int tid = threadIdx.x;
  const int wave = tid >> 6, lane = tid & 63;
  const int lg = lane >> 4, lm = lane & 15;
  const int nwg = gridDim.x * gridDim.y;
  const int id = blockIdx.y * gridDim.x + blockIdx.x;
  const int cpx = nwg >> 3;
  const int swz = (id & 7) * cpx + (id >> 3);
  const int nbx = N >> 7;
  const int m0 = (swz / nbx) * 128, n0 = (swz % nbx) * 128;
  const int wm = (wave >> 1) * 64, wn = (wave & 1) * 64;
  f32x4 acc[4][4] = {};

  int srow[4], scc[4], lbs[4];
#pragma unroll
  for (int it = 0; it < 4; ++it) {
    int ci = it * 256 + wave * 64 + lane;
    srow[it] = ci >> 3;
    scc[it] = (ci & 7) ^ (srow[it] & 7);
    lbs[it] = (it * 256 + wave * 64) * 8;
  }

  for (int k0 = 0; k0 < K; k0 += 64) {
    __syncthreads();
#pragma unroll
    for (int it = 0; it < 4; ++it) {
      size_t ga = (size_t)(m0 + srow[it]) * K + k0 + scc[it] * 8;
      size_t gb = (size_t)(n0 + srow[it]) * K + k0 + scc[it] * 8;
      gload16(&Ah_[ga], &sAh[lbs[it]]);
      gload16(&Bh_[gb], &sBh[lbs[it]]);
    }
    __syncthreads();
    bf16x8 ah[4][2], bh[4][2];
#pragma unroll
    for (int t = 0; t < 4; ++t)
#pragma unroll
      for (int kc = 0; kc < 2; ++kc) {
        int Ra = wm + t * 16 + lm;
        int Rb = wn + t * 16 + lm;
        int pa_ = ((kc * 4 + lg) ^ (Ra & 7)) * 8;
        int pb_ = ((kc * 4 + lg) ^ (Rb & 7)) * 8;
        ah[t][kc] = *reinterpret_cast<const bf16x8*>(&sAh[Ra * 64 + pa_]);
        bh[t][kc] = *reinterpret_cast<const bf16x8*>(&sBh[Rb * 64 + pb_]);
      }
#pragma unroll
    for (int kc = 0; kc < 2; ++kc)
#pragma unroll
      for (int mi = 0; mi < 4; ++mi)
#pragma unroll
        for (int ni = 0; ni < 4; ++ni)
          acc[mi][ni] = __builtin_amdgcn_mfma_f32_16x16x32_bf16(ah[mi][kc], bh[ni][kc], acc[mi][ni], 0, 0, 0);
  }
#pragma unroll
  for (int mi = 0; mi < 4; ++mi)
#pragma unroll
    for (int ni = 0; ni < 4; ++ni)
#pragma unroll
      for (int j = 0; j < 4; ++j) {
        int row = m0 + wm + mi * 16 + lg * 4 + j;
        int col = n0 + wn + ni * 16 + lm;
        Cout[(size_t)row * N + col] = acc[mi][ni][j];
      }
}

// ---------------- RoPE in-place on QKV buffer (vectorized x8): Q scaled by log2e/sqrt(HD) ----------------
__global__ __launch_bounds__(256) void rope2_kernel(ushort* __restrict__ QKV,
                                                    const int* __restrict__ pos,
                                                    const float* __restrict__ cosT,
                                                    const float* __restrict__ sinT) {
  int t = blockIdx.x * 256 + threadIdx.x;  // S*1024/8 threads
  int j0 = (t & 7) * 8;
  int hh = (t >> 3) & 15;
  int s = t >> 7;
  int p = pos[s];
  float cs[8], sn[8];
  *reinterpret_cast<float4*>(&cs[0]) = *reinterpret_cast<const float4*>(&cosT[p * 64 + j0]);
  *reinterpret_cast<float4*>(&cs[4]) = *reinterpret_cast<const float4*>(&cosT[p * 64 + j0 + 4]);
  *reinterpret_cast<float4*>(&sn[0]) = *reinterpret_cast<const float4*>(&sinT[p * 64 + j0]);
  *reinterpret_cast<float4*>(&sn[4]) = *reinterpret_cast<const float4*>(&sinT[p * 64 + j0 + 4]);
  size_t base = (size_t)s * LDQ + hh * HEADDIM + j0;
  union u8 { uint4 v; ushort e[8]; };
  u8 qa, qb, ka, kb;
  qa.v = *reinterpret_cast<const uint4*>(&QKV[base]);
  qb.v = *reinterpret_cast<const uint4*>(&QKV[base + 64]);
  ka.v = *reinterpret_cast<const uint4*>(&QKV[base + DMODEL]);
  kb.v = *reinterpret_cast<const uint4*>(&QKV[base + DMODEL + 64]);
  const float scl = 0.12751742f;  // log2(e)/sqrt(128)
#pragma unroll
  for (int e = 0; e < 8; ++e) {
    float q1 = bf2f(qa.e[e]), q2 = bf2f(qb.e[e]);
    float k1 = bf2f(ka.e[e]), k2 = bf2f(kb.e[e]);
    qa.e[e] = f2bf((q1 * cs[e] - q2 * sn[e]) * scl);
    qb.e[e] = f2bf((q2 * cs[e] + q1 * sn[e]) * scl);
    ka.e[e] = f2bf(k1 * cs[e] - k2 * sn[e]);
    kb.e[e] = f2bf(k2 * cs[e] + k1 * sn[e]);
  }
  *reinterpret_cast<uint4*>(&QKV[base]) = qa.v;
  *reinterpret_cast<uint4*>(&QKV[base + 64]) = qb.v;
  *reinterpret_cast<uint4*>(&QKV[base + DMODEL]) = ka.v;
  *reinterpret_cast<uint4*>(&QKV[base + DMODEL + 64]) = kb.v;
}

// ---------------- V transpose: QKV V-columns -> Vt [2048][S] ----------------
__global__ __launch_bounds__(256) void transpose_kernel(const ushort* __restrict__ Vr,
                                                        ushort* __restrict__ Vt) {
  __shared__ __align__(16) ushort tile[64 * 72];
  int tid = threadIdx.x;
  int s0 = blockIdx.x * 64, c0 = blockIdx.y * 64;
#pragma unroll
  for (int it = 0; it < 2; ++it) {
    int i = tid + it * 256;
    int r = i >> 3, c = i & 7;
    *reinterpret_cast<uint4*>(&tile[r * 72 + c * 8]) =
        *reinterpret_cast<const uint4*>(&Vr[(size_t)(s0 + r) * LDQ + c0 + c * 8]);
  }
  __syncthreads();
#pragma unroll
  for (int it = 0; it < 2; ++it) {
    int i = tid + it * 256;
    int cr = i >> 3, sc = i & 7;
    ushort tmp[8];
#pragma unroll
    for (int j = 0; j < 8; ++j) tmp[j] = tile[(sc * 8 + j) * 72 + cr];
    *reinterpret_cast<uint4*>(&Vt[(size_t)(c0 + cr) * S_LEN + s0 + sc * 8]) =
        *reinterpret_cast<uint4*>(tmp);
  }
}

// ---------------- Flash v15: T15 with CORRECT phase ordering ----------------
// body(t): QK^T(t)->STC  |  softmax(t-1)+PV(t-1) on STP  |  barrier  |  stage K(t+2),V(t+1).
// QK^T(t)'s MFMA results are consumed one full body later (softmax(t) in body(t+1)),
// so ~130 VALU ops + 18 PV MFMAs overlap each QK^T's latency.
// Buffers: K(t) in KtA/KtB by parity, V(t) in VsA/VsB by parity. Every staged load
// crosses exactly one barrier before its first read.

// QK^T(T) from KRD into STC
#define QKT15(STC, KRD)                                                                   \
  {                                                                                       \
    _Pragma("unroll") for (int t2 = 0; t2 < 2; ++t2)                                      \
        _Pragma("unroll") for (int nf = 0; nf < 4; ++nf) STC[t2][nf] = fzero;             \
    __builtin_amdgcn_s_setprio(1);                                                        \
    _Pragma("unroll") for (int nf = 0; nf < 4; ++nf)                                      \
        _Pragma("unroll") for (int kc = 0; kc < 4; ++kc) {                                \
      int pc = (kc * 4 + lg) ^ (lm & 7);                                                  \
      bf16x8 kfrag = *reinterpret_cast<const bf16x8*>(&KRD[(nf * 16 + lm) * 128 + pc * 8]); \
      STC[0][nf] = __builtin_amdgcn_mfma_f32_16x16x32_bf16(kfrag, qh[0][kc], STC[0][nf], 0, 0, 0); \
      STC[1][nf] = __builtin_amdgcn_mfma_f32_16x16x32_bf16(kfrag, qh[1][kc], STC[1][nf], 0, 0, 0); \
    }                                                                                     \
    __builtin_amdgcn_s_setprio(0);                                                        \
  }

// softmax + PV on STP (tile t-1), V from VPR
#define SMPV15(STP, VPR)                                                                  \
  {                                                                                       \
    float m16[2];                                                                         \
    _Pragma("unroll") for (int t2 = 0; t2 < 2; ++t2) {                                    \
      float m = fmaxf(STP[t2][0][0], STP[t2][0][1]);                                      \
      m = fmaxf(fmaxf(m, STP[t2][0][2]), STP[t2][0][3]);                                  \
      m = fmaxf(fmaxf(m, STP[t2][1][0]), STP[t2][1][1]);                                  \
      m = fmaxf(fmaxf(m, STP[t2][1][2]), STP[t2][1][3]);                                  \
      m = fmaxf(fmaxf(m, STP[t2][2][0]), STP[t2][2][1]);                                  \
      m = fmaxf(fmaxf(m, STP[t2][2][2]), STP[t2][2][3]);                                  \
      m = fmaxf(fmaxf(m, STP[t2][3][0]), STP[t2][3][1]);                                  \
      m = fmaxf(fmaxf(m, STP[t2][3][2]), STP[t2][3][3]);                                  \
      m = fmaxf(m, __shfl_xor(m, 16));                                                    \
      m = fmaxf(m, __shfl_xor(m, 32));                                                    \
      m16[t2] = m;                                                                        \
    }                                                                                     \
    bool grow = (m16[0] > mrun[0] + 11.5f) || (m16[1] > mrun[1] + 11.5f);                 \
    if (__any(grow)) {                                                                    \
      _Pragma("unroll") for (int t2 = 0; t2 < 2; ++t2) {                                  \
        float mn = fmaxf(mrun[t2], m16[t2]);                                              \
        float scl = fexp2(mrun[t2] - mn);                                                 \
        mrun[t2] = mn;                                                                    \
        float sj[4];                                                                      \
        _Pragma("unroll") for (int j = 0; j < 4; ++j) sj[j] = __shfl(scl, lg * 4 + j);    \
        _Pragma("unroll") for (int j = 0; j < 4; ++j) osum[t2][j] *= sj[j];               \
        _Pragma("unroll") for (int nb = 0; nb < 8; ++nb)                                  \
            _Pragma("unroll") for (int j = 0; j < 4; ++j) oacc[t2][nb][j] *= sj[j];       \
      }                                                                                   \
    }                                                                                     \
    _Pragma("unroll") for (int t2 = 0; t2 < 2; ++t2)                                      \
        _Pragma("unroll") for (int nf = 0; nf < 4; ++nf)                                  \
            _Pragma("unroll") for (int j = 0; j < 4; ++j)                                 \
                STP[t2][nf][j] = fexp2(STP[t2][nf][j] - mrun[t2]);                        \
    bf16x8 pa[2][2];                                                                      \
    _Pragma("unroll") for (int t2 = 0; t2 < 2; ++t2)                                      \
        _Pragma("unroll") for (int kk = 0; kk < 2; ++kk) {                                \
      union { unsigned int u[4]; bf16x8 v; } w_;                                          \
      w_.u[0] = cvtpk(STP[t2][kk][0], STP[t2][kk][1]);                                    \
      w_.u[1] = cvtpk(STP[t2][kk][2], STP[t2][kk][3]);                                    \
      w_.u[2] = cvtpk(STP[t2][2 + kk][0], STP[t2][2 + kk][1]);                            \
      w_.u[3] = cvtpk(STP[t2][2 + kk][2], STP[t2][2 + kk][3]);                            \
      pa[t2][kk] = w_.v;                                                                  \
    }                                                                                     \
    __builtin_amdgcn_s_setprio(1);                                                        \
    _Pragma("unroll") for (int t2 = 0; t2 < 2; ++t2) {                                    \
      osum[t2] = __builtin_amdgcn_mfma_f32_16x16x32_bf16(pa[t2][0], ones, osum[t2], 0, 0, 0); \
      osum[t2] = __builtin_amdgcn_mfma_f32_16x16x32_bf16(pa[t2][1], ones, osum[t2], 0, 0, 0); \
    }                                                                                     \
    _Pragma("unroll") for (int nb = 0; nb < 8; ++nb)                                      \
        _Pragma("unroll") for (int kk = 0; kk < 2; ++kk) {                                \
      int pc = (kk * 4 + lg) ^ (lm & 7);                                                  \
      bf16x8 vfrag = *reinterpret_cast<const bf16x8*>(&VPR[(nb * 16 + lm) * 64 + pc * 8]); \
      oacc[0][nb] = __builtin_amdgcn_mfma_f32_16x16x32_bf16(pa[0][kk], vfrag, oacc[0][nb], 0, 0, 0); \
      oacc[1][nb] = __builtin_amdgcn_mfma_f32_16x16x32_bf16(pa[1][kk], vfrag, oacc[1][nb], 0, 0, 0); \
    }                                                                                     \
    __builtin_amdgcn_s_setprio(0);                                                        \
  }

// full body(t): STC=st(t), STP=st(t-1), KRD=Kbuf(t%2) (also stage target for K(t+2)),
// VPR=Vbuf((t-1)%2) (PV read; also stage target for V(t+1))
#define BODY15(STC, STP, KRD, VPR, T)                                                     \
  {                                                                                       \
    QKT15(STC, KRD)                                                                       \
    SMPV15(STP, VPR)                                                                      \
    __syncthreads();                                                                      \
    if ((T) + 2 < 64) {                                                                   \
      const size_t ko_ = (size_t)((T) + 2) * 64;                                          \
      _Pragma("unroll") for (int k = 0; k < 4; ++k) gload16(pK[k] + ko_ * LDQ, &KRD[lbs[k]]); \
    }                                                                                     \
    if ((T) + 1 < 64) {                                                                   \
      const size_t vo_ = (size_t)((T) + 1) * 64;                                          \
      _Pragma("unroll") for (int k = 0; k < 4; ++k) gload16(pV[k] + vo_, &VPR[lbs[k]]);   \
    }                                                                                     \
  }

__global__ __launch_bounds__(256, 2) void flash15_kernel(const ushort* __restrict__ QKV,
                                                         const ushort* __restrict__ Vt,
                                                         ushort* __restrict__ Oh) {
  __shared__ __align__(16) ushort KtA[64 * 128];
  __shared__ __align__(16) ushort KtB[64 * 128];
  __shared__ __align__(16) ushort VsA[128 * 64];
  __shared__ __align__(16) ushort VsB[128 * 64];
  const int tid = threadIdx.x;             // 0..255
  const int wave = tid >> 6, lane = tid & 63;
  const int lg = lane >> 4, lm = lane & 15;
  const int id = blockIdx.y * gridDim.x + blockIdx.x;  // 0..511
  const int o = (id & 7) * 64 + (id >> 3);             // XCD swizzle (512 = 8*64)
  const int h = o >> 5;
  const int q0 = (o & 31) * 128;
  const f32x4 fzero = {};

  bf16x8 qh[2][4];
#pragma unroll
  for (int t2 = 0; t2 < 2; ++t2) {
    int qrow = q0 + wave * 32 + t2 * 16 + lm;
#pragma unroll
    for (int kc = 0; kc < 4; ++kc)
      qh[t2][kc] = *reinterpret_cast<const bf16x8*>(
          &QKV[(size_t)qrow * LDQ + h * HEADDIM + kc * 32 + lg * 8]);
  }

  bf16x8 ones;
#pragma unroll
  for (int i = 0; i < 8; ++i) ones[i] = (short)0x3f80;  // bf16 1.0

  auto rho = [](int s) {
    return 32 * ((s >> 4) & 1) + 8 * ((s >> 2) & 3) + 4 * (s >> 5) + (s & 3);
  };
  const ushort* Kb = QKV + DMODEL;  // K columns
  const ushort* pK[4];
  const ushort* pV[4];
  int lbs[4];
#pragma unroll
  for (int k = 0; k < 4; ++k) {
    int ci = k * 256 + wave * 64 + lane;
    int ks = ci >> 4;
    int kcc = (ci & 15) ^ (ks & 7);
    pK[k] = Kb + (size_t)rho(ks) * LDQ + h * HEADDIM + kcc * 8;
    int vd = ci >> 3;
    int vcc = (ci & 7) ^ (vd & 7);
    pV[k] = Vt + (size_t)(h * HEADDIM + vd) * S_LEN + vcc * 8;
    lbs[k] = (k * 256 + wave * 64) * 8;
  }

  f32x4 oacc[2][8] = {};
  f32x4 osum[2] = {};
  float mrun[2];
#pragma unroll
  for (int t2 = 0; t2 < 2; ++t2) mrun[t2] = -3.0e38f;

  f32x4 stA[2][4], stB[2][4];

  // prologue: stage K0->KtA, V0->VsA; drain; stage K1->KtB
#pragma unroll
  for (int k = 0; k < 4; ++k) {
    gload16(pK[k], &KtA[lbs[k]]);
    gload16(pV[k], &VsA[lbs[k]]);
  }
  __syncthreads();
#pragma unroll
  for (int k = 0; k < 4; ++k) gload16(pK[k] + (size_t)64 * LDQ, &KtB[lbs[k]]);

  // body(0): QK^T(0)->stA; barrier; stage K2->KtA, V1->VsB
  QKT15(stA, KtA)
  __syncthreads();
#pragma unroll
  for (int k = 0; k < 4; ++k) {
    gload16(pK[k] + (size_t)128 * LDQ, &KtA[lbs[k]]);
    gload16(pV[k] + 64, &VsB[lbs[k]]);
  }

  // bodies t=1..62 in odd/even pairs, then body(63)
  for (int tp = 0; tp < 31; ++tp) {
    const int t1 = 2 * tp + 1;
    BODY15(stB, stA, KtB, VsA, t1)      // t odd:  st(t)=stB, K=KtB, V(t-1)=VsA
    BODY15(stA, stB, KtA, VsB, t1 + 1)  // t even: st(t)=stA, K=KtA, V(t-1)=VsB
  }
  BODY15(stB, stA, KtB, VsA, 63)        // t=63 (odd)

  // tail: softmax(63)+PV(63); V(63) is odd parity -> VsB
  SMPV15(stB, VsB)

  // epilogue: single bf16 O
#pragma unroll
  for (int t2 = 0; t2 < 2; ++t2) {
    float linv[4];
#pragma unroll
    for (int j = 0; j < 4; ++j) linv[j] = 1.0f / osum[t2][j];
#pragma unroll
    for (int nb = 0; nb < 8; ++nb)
#pragma unroll
      for (int j = 0; j < 4; ++j) {
        int row = q0 + wave * 32 + t2 * 16 + lg * 4 + j;
        int col = h * HEADDIM + nb * 16 + lm;
        Oh[(size_t)row * DMODEL + col] = f2bf(oacc[t2][nb][j] * linv[j]);
      }
  }
}

extern "C" void kernel_launch(void* const* d_in, const int* in_sizes, int n_in,
                              void* d_out, int out_size, void* d_ws, size_t ws_size,
                              hipStream_t stream) {
  (void)in_sizes; (void)n_in; (void)out_size; (void)ws_size;
  const float* X  = (const float*)d_in[0];
  const float* Wq = (const float*)d_in[1];
  const float* Wk = (const float*)d_in[2];
  const float* Wv = (const float*)d_in[3];
  const float* Wo = (const float*)d_in[4];
  const int* pos  = (const int*)d_in[5];
  float* out = (float*)d_out;

  ushort* wb = (ushort*)d_ws;
  const size_t SD = (size_t)S_LEN * DMODEL;       // 8388608 elements
  const size_t DD = (size_t)DMODEL * DMODEL;      // 4194304 elements

  ushort* Xh   = wb;                 // slot0
  ushort* QKV  = wb + 2 * SD;        // slots 2-4: [4096][6144]
  ushort* Vt   = wb + 5 * SD;        // slot5: [2048][4096]
  ushort* W0h  = wb + 6 * SD;        // Wo bf16
  ushort* Wqkv = wb + 7 * SD;        // [6144][2048]
  float* cosT  = (float*)(wb + 9 * SD);
  float* sinT  = cosT + (size_t)S_LEN * 64;
  ushort* OhB  = Wqkv;               // reuse after QKV GEMM done

  prep_all<<<dim3(DD / 1024, 7), 256, 0, stream>>>(X, Wq, Wk, Wv, Wo, Xh, Wqkv, W0h, cosT, sinT);

  gemm_qkv<<<dim3(LDQ / 128, S_LEN / 128), 256, 0, stream>>>(Xh, Wqkv, QKV, S_LEN, LDQ, DMODEL);

  rope2_kernel<<<(S_LEN * 1024 / 8) / 256, 256, 0, stream>>>(QKV, pos, cosT, sinT);
  transpose_kernel<<<dim3(S_LEN / 64, DMODEL / 64), 256, 0, stream>>>(QKV + 2 * DMODEL, Vt);

  flash15_kernel<<<dim3(32, 16), 256, 0, stream>>>(QKV, Vt, OhB);

  dim3 gemmGrid(DMODEL / 128, S_LEN / 128);
  gemm1o64<<<gemmGrid, 256, 0, stream>>>(OhB, W0h, out, S_LEN, DMODEL, DMODEL);
}

// Round 16
// 332.007 us; speedup vs baseline: 1.5028x; 1.0095x over previous
//
#include <hip/hip_runtime.h>
#include <hip/hip_bf16.h>

#define S_LEN 4096
#define DMODEL 2048
#define NHEADS 16
#define HEADDIM 128
#define LDQ 6144  // stride of fused QKV buffer

typedef __attribute__((ext_vector_type(8))) short bf16x8;
typedef __attribute__((ext_vector_type(4))) float f32x4;

__device__ __forceinline__ float bf2f(ushort u) {
  union { unsigned int i; float f; } x; x.i = ((unsigned int)u) << 16; return x.f;
}
__device__ __forceinline__ ushort f2bf(float f) {
  union { float f; unsigned int i; } x; x.f = f;
  unsigned int u = x.i;
  unsigned int r = u + 0x7fffu + ((u >> 16) & 1u);
  return (ushort)(r >> 16);
}
__device__ __forceinline__ unsigned int cvtpk(float a, float b) {
  unsigned int r;
  asm("v_cvt_pk_bf16_f32 %0, %1, %2" : "=v"(r) : "v"(a), "v"(b));
  return r;
}
// fast hardware exp2 (v_exp_f32 IS 2^x); bypasses ocml's precise path
__device__ __forceinline__ float fexp2(float x) {
  float r;
  asm("v_exp_f32 %0, %1" : "=v"(r) : "v"(x));
  return r;
}

__device__ __forceinline__ void gload16(const ushort* g, ushort* l) {
  __builtin_amdgcn_global_load_lds(
      (const __attribute__((address_space(1))) unsigned int*)g,
      (__attribute__((address_space(3))) unsigned int*)l, 16, 0, 0);
}

// ---------------- fused prep: rope table + X convert + weight prep, one launch ----------------
__global__ __launch_bounds__(256) void prep_all(const float* __restrict__ X,
                                                const float* __restrict__ Wq,
                                                const float* __restrict__ Wk,
                                                const float* __restrict__ Wv,
                                                const float* __restrict__ Wo,
                                                ushort* __restrict__ Xh,
                                                ushort* __restrict__ Wqkv,
                                                ushort* __restrict__ Woh,
                                                float* __restrict__ cosT,
                                                float* __restrict__ sinT) {
  int which = blockIdx.y;
  if (which < 4) {  // weights: 4096 blocks each
    int i = (blockIdx.x * 256 + threadIdx.x) * 4;
    const float* src = (which == 0) ? Wq : (which == 1) ? Wk : (which == 2) ? Wv : Wo;
    ushort* dst = (which == 3) ? Woh : (Wqkv + (size_t)which * DMODEL * DMODEL);
    float4 v = *reinterpret_cast<const float4*>(&src[i]);
    ushort4 h;
    h.x = f2bf(v.x); h.y = f2bf(v.y); h.z = f2bf(v.z); h.w = f2bf(v.w);
    *reinterpret_cast<ushort4*>(&dst[i]) = h;
  } else if (which < 6) {  // X: 2 x 4096 blocks
    int i = (((which - 4) * 4096 + blockIdx.x) * 256 + threadIdx.x) * 4;
    float4 v = *reinterpret_cast<const float4*>(&X[i]);
    ushort4 h;
    h.x = f2bf(v.x); h.y = f2bf(v.y); h.z = f2bf(v.z); h.w = f2bf(v.w);
    *reinterpret_cast<ushort4*>(&Xh[i]) = h;
  } else {  // rope table: first 1024 blocks
    if (blockIdx.x >= 1024) return;
    int idx = blockIdx.x * 256 + threadIdx.x;  // S*64
    int t = idx >> 6, j = idx & 63;
    float expo = (float)(2 * j) / 128.0f;
    float inv = 1.0f / powf(10000.0f, expo);
    float f = (float)t * inv;
    cosT[idx] = cosf(f);
    sinT[idx] = sinf(f);
  }
}

// ---------------- fused QKV GEMM: QKV = Xh * Wqkv^T, BK=64, 128x128 tile ----------------
__global__ __launch_bounds__(256) void gemm_qkv(const ushort* __restrict__ Ah_,
                                                const ushort* __restrict__ Bh_,
                                                ushort* __restrict__ Cout,
                                                int M, int N, int K) {
  __shared__ __align__(16) ushort sAh[128 * 64], sBh[128 * 64];
  const int tid = threadIdx.x;
  const int wave = tid >> 6, lane = tid & 63;
  const int lg = lane >> 4, lm = lane & 15;
  const int nwg = gridDim.x * gridDim.y;
  const int id = blockIdx.y * gridDim.x + blockIdx.x;
  const int cpx = nwg >> 3;
  const int swz = (id & 7) * cpx + (id >> 3);
  const int nbx = N >> 7;
  const int m0 = (swz / nbx) * 128, n0 = (swz % nbx) * 128;
  const int wm = (wave >> 1) * 64, wn = (wave & 1) * 64;
  f32x4 acc[4][4] = {};

  int srow[4], scc[4], lbs[4];
#pragma unroll
  for (int it = 0; it < 4; ++it) {
    int ci = it * 256 + wave * 64 + lane;
    srow[it] = ci >> 3;
    scc[it] = (ci & 7) ^ (srow[it] & 7);
    lbs[it] = (it * 256 + wave * 64) * 8;
  }

  for (int k0 = 0; k0 < K; k0 += 64) {
    __syncthreads();
#pragma unroll
    for (int it = 0; it < 4; ++it) {
      size_t ga = (size_t)(m0 + srow[it]) * K + k0 + scc[it] * 8;
      size_t gb = (size_t)(n0 + srow[it]) * K + k0 + scc[it] * 8;
      gload16(&Ah_[ga], &sAh[lbs[it]]);
      gload16(&Bh_[gb], &sBh[lbs[it]]);
    }
    __syncthreads();
    bf16x8 ah[4][2], bh[4][2];
#pragma unroll
    for (int t = 0; t < 4; ++t)
#pragma unroll
      for (int kc = 0; kc < 2; ++kc) {
        int Ra = wm + t * 16 + lm;
        int Rb = wn + t * 16 + lm;
        int pa_ = ((kc * 4 + lg) ^ (Ra & 7)) * 8;
        int pb_ = ((kc * 4 + lg) ^ (Rb & 7)) * 8;
        ah[t][kc] = *reinterpret_cast<const bf16x8*>(&sAh[Ra * 64 + pa_]);
        bh[t][kc] = *reinterpret_cast<const bf16x8*>(&sBh[Rb * 64 + pb_]);
      }
#pragma unroll
    for (int kc = 0; kc < 2; ++kc)
#pragma unroll
      for (int mi = 0; mi < 4; ++mi)
#pragma unroll
        for (int ni = 0; ni < 4; ++ni)
          acc[mi][ni] = __builtin_amdgcn_mfma_f32_16x16x32_bf16(ah[mi][kc], bh[ni][kc], acc[mi][ni], 0, 0, 0);
  }
#pragma unroll
  for (int mi = 0; mi < 4; ++mi)
#pragma unroll
    for (int ni = 0; ni < 4; ++ni)
#pragma unroll
      for (int j = 0; j < 4; ++j) {
        int row = m0 + wm + mi * 16 + lg * 4 + j;
        int col = n0 + wn + ni * 16 + lm;
        Cout[(size_t)row * N + col] = f2bf(acc[mi][ni][j]);
      }
}

// ---------------- 1-term final GEMM, BK=64 structure: out = Oh * Woh^T (f32 out) ----------------
__global__ __launch_bounds__(256) void gemm1o64(const ushort* __restrict__ Ah_,
                                                const ushort* __restrict__ Bh_,
                                                float* __restrict__ Cout,
                                                int M, int N, int K) {
  __shared__ __align__(16) ushort sAh[128 * 64], sBh[128 * 64];
  const int tid = threadIdx.x;
  const int wave = tid >> 6, lane = tid & 63;
  const int lg = lane >> 4, lm = lane & 15;
  const int nwg = gridDim.x * gridDim.y;
  const int id = blockIdx.y * gridDim.x + blockIdx.x;
  const int cpx = nwg >> 3;
  const int swz = (id & 7) * cpx + (id >> 3);
  const int nbx = N >> 7;
  const int m0 = (swz / nbx) * 128, n0 = (swz % nbx) * 128;
  const int wm = (wave >> 1) * 64, wn = (wave & 1) * 64;
  f32x4 acc[4][4] = {};

  int srow[4], scc[4], lbs[4];
#pragma unroll
  for (int it = 0; it < 4; ++it) {
    int ci = it * 256 + wave * 64 + lane;
    srow[it] = ci >> 3;
    scc[it] = (ci & 7) ^ (srow[it] & 7);
    lbs[it] = (it * 256 + wave * 64) * 8;
  }

  for (int k0 = 0; k0 < K; k0 += 64) {
    __syncthreads();
#pragma unroll
    for (int it = 0; it < 4; ++it) {
      size_t ga = (size_t)(m0 + srow[it]) * K + k0 + scc[it] * 8;
      size_t gb = (size_t)(n0 + srow[it]) * K + k0 + scc[it] * 8;
      gload16(&Ah_[ga], &sAh[lbs[it]]);
      gload16(&Bh_[gb], &sBh[lbs[it]]);
    }
    __syncthreads();
    bf16x8 ah[4][2], bh[4][2];
#pragma unroll
    for (int t = 0; t < 4; ++t)
#pragma unroll
      for (int kc = 0; kc < 2; ++kc) {
        int Ra = wm + t * 16 + lm;
        int Rb = wn + t * 16 + lm;
        int pa_ = ((kc * 4 + lg) ^ (Ra & 7)) * 8;
        int pb_ = ((kc * 4 + lg) ^ (Rb & 7)) * 8;
        ah[t][kc] = *reinterpret_cast<const bf16x8*>(&sAh[Ra * 64 + pa_]);
        bh[t][kc] = *reinterpret_cast<const bf16x8*>(&sBh[Rb * 64 + pb_]);
      }
#pragma unroll
    for (int kc = 0; kc < 2; ++kc)
#pragma unroll
      for (int mi = 0; mi < 4; ++mi)
#pragma unroll
        for (int ni = 0; ni < 4; ++ni)
          acc[mi][ni] = __builtin_amdgcn_mfma_f32_16x16x32_bf16(ah[mi][kc], bh[ni][kc], acc[mi][ni], 0, 0, 0);
  }
#pragma unroll
  for (int mi = 0; mi < 4; ++mi)
#pragma unroll
    for (int ni = 0; ni < 4; ++ni)
#pragma unroll
      for (int j = 0; j < 4; ++j) {
        int row = m0 + wm + mi * 16 + lg * 4 + j;
        int col = n0 + wn + ni * 16 + lm;
        Cout[(size_t)row * N + col] = acc[mi][ni][j];
      }
}

// ---------------- fused postproc: RoPE (Q,K) + V transpose, one launch ----------------
// blockIdx.y < 32: V-transpose blocks (2D: bx = s-tile, by = col-tile)
// blockIdx.y >= 32: RoPE blocks (linear id over S*1024/8 pairs-of-8)
__global__ __launch_bounds__(256) void postproc_kernel(ushort* __restrict__ QKV,
                                                       const int* __restrict__ pos,
                                                       const float* __restrict__ cosT,
                                                       const float* __restrict__ sinT,
                                                       ushort* __restrict__ Vt) {
  if (blockIdx.y < 32) {
    // ---- V transpose: QKV V-columns [S][2048 @ off 4096, ld 6144] -> Vt [2048][S]
    __shared__ __align__(16) ushort tile[64 * 72];
    const ushort* Vr = QKV + 2 * DMODEL;
    int tid = threadIdx.x;
    int s0 = blockIdx.x * 64, c0 = blockIdx.y * 64;
#pragma unroll
    for (int it = 0; it < 2; ++it) {
      int i = tid + it * 256;
      int r = i >> 3, c = i & 7;
      *reinterpret_cast<uint4*>(&tile[r * 72 + c * 8]) =
          *reinterpret_cast<const uint4*>(&Vr[(size_t)(s0 + r) * LDQ + c0 + c * 8]);
    }
    __syncthreads();
#pragma unroll
    for (int it = 0; it < 2; ++it) {
      int i = tid + it * 256;
      int cr = i >> 3, sc = i & 7;
      ushort tmp[8];
#pragma unroll
      for (int j = 0; j < 8; ++j) tmp[j] = tile[(sc * 8 + j) * 72 + cr];
      *reinterpret_cast<uint4*>(&Vt[(size_t)(c0 + cr) * S_LEN + s0 + sc * 8]) =
          *reinterpret_cast<uint4*>(tmp);
    }
  } else {
    // ---- RoPE in-place on Q (scaled log2e/sqrt(HD)) and K, vectorized x8
    int t = ((blockIdx.y - 32) * 64 + blockIdx.x) * 256 + threadIdx.x;  // 0..S*128-1
    int j0 = (t & 7) * 8;
    int hh = (t >> 3) & 15;
    int s = t >> 7;
    int p = pos[s];
    float cs[8], sn[8];
    *reinterpret_cast<float4*>(&cs[0]) = *reinterpret_cast<const float4*>(&cosT[p * 64 + j0]);
    *reinterpret_cast<float4*>(&cs[4]) = *reinterpret_cast<const float4*>(&cosT[p * 64 + j0 + 4]);
    *reinterpret_cast<float4*>(&sn[0]) = *reinterpret_cast<const float4*>(&sinT[p * 64 + j0]);
    *reinterpret_cast<float4*>(&sn[4]) = *reinterpret_cast<const float4*>(&sinT[p * 64 + j0 + 4]);
    size_t base = (size_t)s * LDQ + hh * HEADDIM + j0;
    union u8 { uint4 v; ushort e[8]; };
    u8 qa, qb, ka, kb;
    qa.v = *reinterpret_cast<const uint4*>(&QKV[base]);
    qb.v = *reinterpret_cast<const uint4*>(&QKV[base + 64]);
    ka.v = *reinterpret_cast<const uint4*>(&QKV[base + DMODEL]);
    kb.v = *reinterpret_cast<const uint4*>(&QKV[base + DMODEL + 64]);
    const float scl = 0.12751742f;  // log2(e)/sqrt(128)
#pragma unroll
    for (int e = 0; e < 8; ++e) {
      float q1 = bf2f(qa.e[e]), q2 = bf2f(qb.e[e]);
      float k1 = bf2f(ka.e[e]), k2 = bf2f(kb.e[e]);
      qa.e[e] = f2bf((q1 * cs[e] - q2 * sn[e]) * scl);
      qb.e[e] = f2bf((q2 * cs[e] + q1 * sn[e]) * scl);
      ka.e[e] = f2bf(k1 * cs[e] - k2 * sn[e]);
      kb.e[e] = f2bf(k2 * cs[e] + k1 * sn[e]);
    }
    *reinterpret_cast<uint4*>(&QKV[base]) = qa.v;
    *reinterpret_cast<uint4*>(&QKV[base + 64]) = qb.v;
    *reinterpret_cast<uint4*>(&QKV[base + DMODEL]) = ka.v;
    *reinterpret_cast<uint4*>(&QKV[base + DMODEL + 64]) = kb.v;
  }
}

// ---------------- Flash v15: T15 phase ordering (round-15 champion, unchanged) ----------------
#define QKT15(STC, KRD)                                                                   \
  {                                                                                       \
    _Pragma("unroll") for (int t2 = 0; t2 < 2; ++t2)                                      \
        _Pragma("unroll") for (int nf = 0; nf < 4; ++nf) STC[t2][nf] = fzero;             \
    __builtin_amdgcn_s_setprio(1);                                                        \
    _Pragma("unroll") for (int nf = 0; nf < 4; ++nf)                                      \
        _Pragma("unroll") for (int kc = 0; kc < 4; ++kc) {                                \
      int pc = (kc * 4 + lg) ^ (lm & 7);                                                  \
      bf16x8 kfrag = *reinterpret_cast<const bf16x8*>(&KRD[(nf * 16 + lm) * 128 + pc * 8]); \
      STC[0][nf] = __builtin_amdgcn_mfma_f32_16x16x32_bf16(kfrag, qh[0][kc], STC[0][nf], 0, 0, 0); \
      STC[1][nf] = __builtin_amdgcn_mfma_f32_16x16x32_bf16(kfrag, qh[1][kc], STC[1][nf], 0, 0, 0); \
    }                                                                                     \
    __builtin_amdgcn_s_setprio(0);                                                        \
  }

#define SMPV15(STP, VPR)                                                                  \
  {                                                                                       \
    float m16[2];                                                                         \
    _Pragma("unroll") for (int t2 = 0; t2 < 2; ++t2) {                                    \
      float m = fmaxf(STP[t2][0][0], STP[t2][0][1]);                                      \
      m = fmaxf(fmaxf(m, STP[t2][0][2]), STP[t2][0][3]);                                  \
      m = fmaxf(fmaxf(m, STP[t2][1][0]), STP[t2][1][1]);                                  \
      m = fmaxf(fmaxf(m, STP[t2][1][2]), STP[t2][1][3]);                                  \
      m = fmaxf(fmaxf(m, STP[t2][2][0]), STP[t2][2][1]);                                  \
      m = fmaxf(fmaxf(m, STP[t2][2][2]), STP[t2][2][3]);                                  \
      m = fmaxf(fmaxf(m, STP[t2][3][0]), STP[t2][3][1]);                                  \
      m = fmaxf(fmaxf(m, STP[t2][3][2]), STP[t2][3][3]);                                  \
      m = fmaxf(m, __shfl_xor(m, 16));                                                    \
      m = fmaxf(m, __shfl_xor(m, 32));                                                    \
      m16[t2] = m;                                                                        \
    }                                                                                     \
    bool grow = (m16[0] > mrun[0] + 11.5f) || (m16[1] > mrun[1] + 11.5f);                 \
    if (__any(grow)) {                                                                    \
      _Pragma("unroll") for (int t2 = 0; t2 < 2; ++t2) {                                  \
        float mn = fmaxf(mrun[t2], m16[t2]);                                              \
        float scl = fexp2(mrun[t2] - mn);                                                 \
        mrun[t2] = mn;                                                                    \
        float sj[4];                                                                      \
        _Pragma("unroll") for (int j = 0; j < 4; ++j) sj[j] = __shfl(scl, lg * 4 + j);    \
        _Pragma("unroll") for (int j = 0; j < 4; ++j) osum[t2][j] *= sj[j];               \
        _Pragma("unroll") for (int nb = 0; nb < 8; ++nb)                                  \
            _Pragma("unroll") for (int j = 0; j < 4; ++j) oacc[t2][nb][j] *= sj[j];       \
      }                                                                                   \
    }                                                                                     \
    _Pragma("unroll") for (int t2 = 0; t2 < 2; ++t2)                                      \
        _Pragma("unroll") for (int nf = 0; nf < 4; ++nf)                                  \
            _Pragma("unroll") for (int j = 0; j < 4; ++j)                                 \
                STP[t2][nf][j] = fexp2(STP[t2][nf][j] - mrun[t2]);                        \
    bf16x8 pa[2][2];                                                                      \
    _Pragma("unroll") for (int t2 = 0; t2 < 2; ++t2)                                      \
        _Pragma("unroll") for (int kk = 0; kk < 2; ++kk) {                                \
      union { unsigned int u[4]; bf16x8 v; } w_;                                          \
      w_.u[0] = cvtpk(STP[t2][kk][0], STP[t2][kk][1]);                                    \
      w_.u[1] = cvtpk(STP[t2][kk][2], STP[t2][kk][3]);                                    \
      w_.u[2] = cvtpk(STP[t2][2 + kk][0], STP[t2][2 + kk][1]);                            \
      w_.u[3] = cvtpk(STP[t2][2 + kk][2], STP[t2][2 + kk][3]);                            \
      pa[t2][kk] = w_.v;                                                                  \
    }                                                                                     \
    __builtin_amdgcn_s_setprio(1);                                                        \
    _Pragma("unroll") for (int t2 = 0; t2 < 2; ++t2) {                                    \
      osum[t2] = __builtin_amdgcn_mfma_f32_16x16x32_bf16(pa[t2][0], ones, osum[t2], 0, 0, 0); \
      osum[t2] = __builtin_amdgcn_mfma_f32_16x16x32_bf16(pa[t2][1], ones, osum[t2], 0, 0, 0); \
    }                                                                                     \
    _Pragma("unroll") for (int nb = 0; nb < 8; ++nb)                                      \
        _Pragma("unroll") for (int kk = 0; kk < 2; ++kk) {                                \
      int pc = (kk * 4 + lg) ^ (lm & 7);                                                  \
      bf16x8 vfrag = *reinterpret_cast<const bf16x8*>(&VPR[(nb * 16 + lm) * 64 + pc * 8]); \
      oacc[0][nb] = __builtin_amdgcn_mfma_f32_16x16x32_bf16(pa[0][kk], vfrag, oacc[0][nb], 0, 0, 0); \
      oacc[1][nb] = __builtin_amdgcn_mfma_f32_16x16x32_bf16(pa[1][kk], vfrag, oacc[1][nb], 0, 0, 0); \
    }                                                                                     \
    __builtin_amdgcn_s_setprio(0);                                                        \
  }

#define BODY15(STC, STP, KRD, VPR, T)                                                     \
  {                                                                                       \
    QKT15(STC, KRD)                                                                       \
    SMPV15(STP, VPR)                                                                      \
    __syncthreads();                                                                      \
    if ((T) + 2 < 64) {                                                                   \
      const size_t ko_ = (size_t)((T) + 2) * 64;                                          \
      _Pragma("unroll") for (int k = 0; k < 4; ++k) gload16(pK[k] + ko_ * LDQ, &KRD[lbs[k]]); \
    }                                                                                     \
    if ((T) + 1 < 64) {                                                                   \
      const size_t vo_ = (size_t)((T) + 1) * 64;                                          \
      _Pragma("unroll") for (int k = 0; k < 4; ++k) gload16(pV[k] + vo_, &VPR[lbs[k]]);   \
    }                                                                                     \
  }

__global__ __launch_bounds__(256, 2) void flash15_kernel(const ushort* __restrict__ QKV,
                                                         const ushort* __restrict__ Vt,
                                                         ushort* __restrict__ Oh) {
  __shared__ __align__(16) ushort KtA[64 * 128];
  __shared__ __align__(16) ushort KtB[64 * 128];
  __shared__ __align__(16) ushort VsA[128 * 64];
  __shared__ __align__(16) ushort VsB[128 * 64];
  const int tid = threadIdx.x;             // 0..255
  const int wave = tid >> 6, lane = tid & 63;
  const int lg = lane >> 4, lm = lane & 15;
  const int id = blockIdx.y * gridDim.x + blockIdx.x;  // 0..511
  const int o = (id & 7) * 64 + (id >> 3);             // XCD swizzle (512 = 8*64)
  const int h = o >> 5;
  const int q0 = (o & 31) * 128;
  const f32x4 fzero = {};

  bf16x8 qh[2][4];
#pragma unroll
  for (int t2 = 0; t2 < 2; ++t2) {
    int qrow = q0 + wave * 32 + t2 * 16 + lm;
#pragma unroll
    for (int kc = 0; kc < 4; ++kc)
      qh[t2][kc] = *reinterpret_cast<const bf16x8*>(
          &QKV[(size_t)qrow * LDQ + h * HEADDIM + kc * 32 + lg * 8]);
  }

  bf16x8 ones;
#pragma unroll
  for (int i = 0; i < 8; ++i) ones[i] = (short)0x3f80;  // bf16 1.0

  auto rho = [](int s) {
    return 32 * ((s >> 4) & 1) + 8 * ((s >> 2) & 3) + 4 * (s >> 5) + (s & 3);
  };
  const ushort* Kb = QKV + DMODEL;  // K columns
  const ushort* pK[4];
  const ushort* pV[4];
  int lbs[4];
#pragma unroll
  for (int k = 0; k < 4; ++k) {
    int ci = k * 256 + wave * 64 + lane;
    int ks = ci >> 4;
    int kcc = (ci & 15) ^ (ks & 7);
    pK[k] = Kb + (size_t)rho(ks) * LDQ + h * HEADDIM + kcc * 8;
    int vd = ci >> 3;
    int vcc = (ci & 7) ^ (vd & 7);
    pV[k] = Vt + (size_t)(h * HEADDIM + vd) * S_LEN + vcc * 8;
    lbs[k] = (k * 256 + wave * 64) * 8;
  }

  f32x4 oacc[2][8] = {};
  f32x4 osum[2] = {};
  float mrun[2];
#pragma unroll
  for (int t2 = 0; t2 < 2; ++t2) mrun[t2] = -3.0e38f;

  f32x4 stA[2][4], stB[2][4];

  // prologue: stage K0->KtA, V0->VsA; drain; stage K1->KtB
#pragma unroll
  for (int k = 0; k < 4; ++k) {
    gload16(pK[k], &KtA[lbs[k]]);
    gload16(pV[k], &VsA[lbs[k]]);
  }
  __syncthreads();
#pragma unroll
  for (int k = 0; k < 4; ++k) gload16(pK[k] + (size_t)64 * LDQ, &KtB[lbs[k]]);

  // body(0): QK^T(0)->stA; barrier; stage K2->KtA, V1->VsB
  QKT15(stA, KtA)
  __syncthreads();
#pragma unroll
  for (int k = 0; k < 4; ++k) {
    gload16(pK[k] + (size_t)128 * LDQ, &KtA[lbs[k]]);
    gload16(pV[k] + 64, &VsB[lbs[k]]);
  }

  // bodies t=1..62 in odd/even pairs, then body(63)
  for (int tp = 0; tp < 31; ++tp) {
    const int t1 = 2 * tp + 1;
    BODY15(stB, stA, KtB, VsA, t1)      // t odd:  st(t)=stB, K=KtB, V(t-1)=VsA
    BODY15(stA, stB, KtA, VsB, t1 + 1)  // t even: st(t)=stA, K=KtA, V(t-1)=VsB
  }
  BODY15(stB, stA, KtB, VsA, 63)        // t=63 (odd)

  // tail: softmax(63)+PV(63); V(63) is odd parity -> VsB
  SMPV15(stB, VsB)

  // epilogue: single bf16 O
#pragma unroll
  for (int t2 = 0; t2 < 2; ++t2) {
    float linv[4];
#pragma unroll
    for (int j = 0; j < 4; ++j) linv[j] = 1.0f / osum[t2][j];
#pragma unroll
    for (int nb = 0; nb < 8; ++nb)
#pragma unroll
      for (int j = 0; j < 4; ++j) {
        int row = q0 + wave * 32 + t2 * 16 + lg * 4 + j;
        int col = h * HEADDIM + nb * 16 + lm;
        Oh[(size_t)row * DMODEL + col] = f2bf(oacc[t2][nb][j] * linv[j]);
      }
  }
}

extern "C" void kernel_launch(void* const* d_in, const int* in_sizes, int n_in,
                              void* d_out, int out_size, void* d_ws, size_t ws_size,
                              hipStream_t stream) {
  (void)in_sizes; (void)n_in; (void)out_size; (void)ws_size;
  const float* X  = (const float*)d_in[0];
  const float* Wq = (const float*)d_in[1];
  const float* Wk = (const float*)d_in[2];
  const float* Wv = (const float*)d_in[3];
  const float* Wo = (const float*)d_in[4];
  const int* pos  = (const int*)d_in[5];
  float* out = (float*)d_out;

  ushort* wb = (ushort*)d_ws;
  const size_t SD = (size_t)S_LEN * DMODEL;       // 8388608 elements
  const size_t DD = (size_t)DMODEL * DMODEL;      // 4194304 elements

  ushort* Xh   = wb;                 // slot0
  ushort* QKV  = wb + 2 * SD;        // slots 2-4: [4096][6144]
  ushort* Vt   = wb + 5 * SD;        // slot5: [2048][4096]
  ushort* W0h  = wb + 6 * SD;        // Wo bf16
  ushort* Wqkv = wb + 7 * SD;        // [6144][2048]
  float* cosT  = (float*)(wb + 9 * SD);
  float* sinT  = cosT + (size_t)S_LEN * 64;
  ushort* OhB  = Wqkv;               // reuse after QKV GEMM done

  prep_all<<<dim3(DD / 1024, 7), 256, 0, stream>>>(X, Wq, Wk, Wv, Wo, Xh, Wqkv, W0h, cosT, sinT);

  gemm_qkv<<<dim3(LDQ / 128, S_LEN / 128), 256, 0, stream>>>(Xh, Wqkv, QKV, S_LEN, LDQ, DMODEL);

  // fused RoPE + V-transpose: y<32 transpose tiles (64x32), y in [32,64) rope blocks (2048)
  postproc_kernel<<<dim3(64, 64), 256, 0, stream>>>(QKV, pos, cosT, sinT, Vt);

  flash15_kernel<<<dim3(32, 16), 256, 0, stream>>>(QKV, Vt, OhB);

  dim3 gemmGrid(DMODEL / 128, S_LEN / 128);
  gemm1o64<<<gemmGrid, 256, 0, stream>>>(OhB, W0h, out, S_LEN, DMODEL, DMODEL);
}